// Round 23
// baseline (133.196 us; speedup 1.0000x reference)
//
#include <hip/hip_runtime.h>
#include <hip/hip_bf16.h>
#include <stdint.h>

#define D_MODEL 1024
#define NH 16
#define DH 64
#define SEQ 2048
#define MROWS 4096   // B*S
#define LOG2E 1.44269504088896340736f

typedef unsigned short ushort_t;
typedef __attribute__((ext_vector_type(4))) float f32x4;
typedef __attribute__((ext_vector_type(16))) float f32x16;
typedef __attribute__((ext_vector_type(4))) unsigned short us4;
typedef __attribute__((ext_vector_type(8))) unsigned short us8;
typedef __attribute__((ext_vector_type(4))) unsigned int u32x4;
typedef __attribute__((ext_vector_type(8))) __bf16 bf16x8;

__device__ __forceinline__ f32x4 mfma16(us8 a, us8 b, f32x4 c) {
    return __builtin_amdgcn_mfma_f32_16x16x32_bf16(
        __builtin_bit_cast(bf16x8, a), __builtin_bit_cast(bf16x8, b), c, 0, 0, 0);
}
__device__ __forceinline__ f32x16 mfma32(us8 a, us8 b, f32x16 c) {
    return __builtin_amdgcn_mfma_f32_32x32x16_bf16(
        __builtin_bit_cast(bf16x8, a), __builtin_bit_cast(bf16x8, b), c, 0, 0, 0);
}

// packed f32x2 -> bf16x2, RNE (verified == manual RNE in rounds 7-21)
__device__ __forceinline__ unsigned int cvtpk(float lo, float hi) {
    unsigned int r;
    asm("v_cvt_pk_bf16_f32 %0, %1, %2" : "=v"(r) : "v"(lo), "v"(hi));
    return r;
}
// single f32 -> bf16 (1 VALU op)
__device__ __forceinline__ ushort_t f2bf1(float f) {
    return (ushort_t)(cvtpk(f, f) & 0xffffu);
}
__device__ __forceinline__ float bf2f(ushort_t u) {
    union { unsigned int u; float f; } v; v.u = ((unsigned int)u) << 16;
    return v.f;
}

__device__ __forceinline__ float exp2_fast(float x) {
#if __has_builtin(__builtin_amdgcn_exp2f)
    return __builtin_amdgcn_exp2f(x);
#else
    float r; asm("v_exp_f32 %0, %1" : "=v"(r) : "v"(x)); return r;
#endif
}

// async global->LDS, 16B per lane; LDS base wave-uniform, lane i at base+i*16
__device__ __forceinline__ void gload16(const void* g, void* l) {
    __builtin_amdgcn_global_load_lds(
        (const __attribute__((address_space(1))) void*)g,
        (__attribute__((address_space(3))) void*)l, 16, 0, 0);
}

// ---------------------------------------------------------------------------
// fused fp32 -> bf16 convert; z picks pair; n4 = float4 count
// ---------------------------------------------------------------------------
__global__ __launch_bounds__(256) void conv_multi(
    const float* __restrict__ s0, ushort_t* __restrict__ d0,
    const float* __restrict__ s1, ushort_t* __restrict__ d1,
    const float* __restrict__ s2, ushort_t* __restrict__ d2,
    const float* __restrict__ s3, ushort_t* __restrict__ d3, int n4)
{
    int z = blockIdx.z;
    const float* s = z == 0 ? s0 : z == 1 ? s1 : z == 2 ? s2 : s3;
    ushort_t* d    = z == 0 ? d0 : z == 1 ? d1 : z == 2 ? d2 : d3;
    int i = blockIdx.x * 256 + threadIdx.x;
    int stride = gridDim.x * 256;
    for (; i < n4; i += stride) {
        float4 v = ((const float4*)s)[i];
        uint2 pr;
        pr.x = cvtpk(v.x, v.y);
        pr.y = cvtpk(v.z, v.w);
        ((uint2*)d)[i] = pr;
    }
}

// ---------------------------------------------------------------------------
// mask tile flags at 64x64 granularity
// ---------------------------------------------------------------------------
__global__ __launch_bounds__(256) void mask_flags(const float* __restrict__ mask,
                                                  int* __restrict__ flags)
{
    int qt = blockIdx.x, kt = blockIdx.y;
    int t = threadIdx.x;
    bool nz = false;
#pragma unroll
    for (int i = 0; i < 4; i++) {
        int idx = t + i * 256;               // 1024 float4: 64 rows x 16
        int row = idx >> 4, c4 = (idx & 15) * 4;
        float4 v = *(const float4*)(mask + (size_t)(qt * 64 + row) * SEQ + kt * 64 + c4);
        nz |= (v.x != 0.f) | (v.y != 0.f) | (v.z != 0.f) | (v.w != 0.f);
    }
    if (__any((int)nz) && (t & 63) == 0) atomicOr(&flags[qt * 32 + kt], 1);
}

// ---------------------------------------------------------------------------
// KV-split combine: AO = (O1 + O2) / (l1 + l2). Max-free softmax makes
// partials exactly additive. 524288 chunks of 8 -> grid 2048 x 256
// (r22 bug: launched 512 -> 3/4 of AO left holding stale Ak data).
// ---------------------------------------------------------------------------
__global__ __launch_bounds__(256) void combine(const ushort_t* __restrict__ O1,
                                               const ushort_t* __restrict__ O2,
                                               const float* __restrict__ L1,
                                               const float* __restrict__ L2,
                                               ushort_t* __restrict__ AO)
{
    int i = blockIdx.x * 256 + threadIdx.x;       // 524288 chunks of 8
    int base = i * 8;
    int row = base >> 10, h = (base & 1023) >> 6;
    float invl = 1.f / (L1[row * NH + h] + L2[row * NH + h]);
    us8 a = *(const us8*)(O1 + base);
    us8 c = *(const us8*)(O2 + base);
    float f[8];
#pragma unroll
    for (int e = 0; e < 8; e++) f[e] = (bf2f(a[e]) + bf2f(c[e])) * invl;
    u32x4 o;
    o[0] = cvtpk(f[0], f[1]); o[1] = cvtpk(f[2], f[3]);
    o[2] = cvtpk(f[4], f[5]); o[3] = cvtpk(f[6], f[7]);
    *(u32x4*)(AO + base) = o;
}

// ---------------------------------------------------------------------------
// GEMM staging, XOR-SWIZZLED LDS (r18-verified: conflicts 14.16M -> 0)
// ---------------------------------------------------------------------------
__device__ __forceinline__ void stageB_bf16(const ushort_t* __restrict__ B,
                                            int n0, int t, int w, int k0,
                                            ushort_t* sB)
{
#pragma unroll
    for (int r = 0; r < 2; r++) {
        int chunk = r * 256 + t;
        int row = chunk >> 3, cc = (chunk & 7) ^ (row & 7);
        gload16(B + (size_t)(n0 + row) * D_MODEL + k0 + cc * 8,
                &sB[(r * 256 + w * 64) * 8]);
    }
}

__device__ __forceinline__ void stageA_bf16(const ushort_t* __restrict__ A,
                                            int m0, int t, int w, int k0,
                                            ushort_t* sA)
{
#pragma unroll
    for (int r = 0; r < 4; r++) {
        int chunk = r * 256 + t;                   // 1024 chunks of 8 bf16
        int row = chunk >> 3, cc = (chunk & 7) ^ (row & 7);
        gload16(A + (size_t)(m0 + row) * D_MODEL + k0 + cc * 8,
                &sA[(r * 256 + w * 64) * 8]);
    }
}

__device__ __forceinline__ void stageA_f32(const float* __restrict__ A,
                                           int m0, int t, int k0,
                                           ushort_t* sA)
{
#pragma unroll
    for (int r = 0; r < 4; r++) {
        int chunk = r * 256 + t;
        int row = chunk >> 3, c = chunk & 7;
        const float* src = A + (size_t)(m0 + row) * D_MODEL + k0 + c * 8;
        float4 v0 = *(const float4*)src;
        float4 v1 = *(const float4*)(src + 4);
        u32x4 pw;
        pw[0] = cvtpk(v0.x, v0.y); pw[1] = cvtpk(v0.z, v0.w);
        pw[2] = cvtpk(v1.x, v1.y); pw[3] = cvtpk(v1.z, v1.w);
        int by = (row * 128 + c * 16) ^ ((row & 7) << 4);   // swizzled dest
        *(u32x4*)((char*)sA + by) = pw;
    }
}

// ---------------------------------------------------------------------------
// fused QKV projection (r20/21-verified): z=0 Aq->Qb (scaled), z=1 Ak->Kb,
// z=2 Av (or fp32 vx fallback) -> VT. 2-phase dbuf, swizzled LDS.
// ---------------------------------------------------------------------------
__global__ __launch_bounds__(256) void gemm_qkv(const ushort_t* __restrict__ Aq,
                                                const ushort_t* __restrict__ Ak,
                                                const ushort_t* __restrict__ Av,
                                                const float* __restrict__ vx,
                                                const ushort_t* __restrict__ Wq,
                                                const ushort_t* __restrict__ Wk,
                                                const ushort_t* __restrict__ Wv,
                                                ushort_t* __restrict__ Qo,
                                                ushort_t* __restrict__ Ko,
                                                ushort_t* __restrict__ VT)
{
    __shared__ ushort_t sA[2][128 * 64];
    __shared__ ushort_t sB[2][64 * 64];
    const int z = blockIdx.z;
    const ushort_t* Abf = z == 0 ? Aq : z == 1 ? Ak : Av;
    const ushort_t* W = z == 0 ? Wq : z == 1 ? Wk : Wv;
    const bool f32path = (z == 2) && (Av == nullptr);
    const int t = threadIdx.x, lane = t & 63, w = t >> 6;
    const int lr = lane & 15, lg = lane >> 4;
    const int wm = (w >> 1) * 64, wn = (w & 1) * 32;
    const int m0 = blockIdx.x * 128, n0 = blockIdx.y * 64;

    f32x4 acc[4][2];
    f32x4 zero = {0.f, 0.f, 0.f, 0.f};
#pragma unroll
    for (int i = 0; i < 4; i++)
#pragma unroll
        for (int j = 0; j < 2; j++) acc[i][j] = zero;

    stageB_bf16(W, n0, t, w, 0, &sB[0][0]);
    if (!f32path) stageA_bf16(Abf, m0, t, w, 0, &sA[0][0]);
    else          stageA_f32(vx, m0, t, 0, &sA[0][0]);
    __syncthreads();

    for (int it = 0; it < D_MODEL / 64; ++it) {
        const int cur = it & 1;
        const char* cA = (const char*)&sA[cur][0];
        const char* cB = (const char*)&sB[cur][0];
        const bool more = (it + 1 < D_MODEL / 64);

        us8 af[4][2], bfr[2][2];
#pragma unroll
        for (int i = 0; i < 4; i++)
#pragma unroll
            for (int ks = 0; ks < 2; ks++) {
                int row = wm + i * 16 + lr;
                af[i][ks] = *(const us8*)(cA + ((row * 128 + (ks * 32 + 8 * lg) * 2)
                                                ^ ((row & 7) << 4)));
            }
#pragma unroll
        for (int j = 0; j < 2; j++)
#pragma unroll
            for (int ks = 0; ks < 2; ks++) {
                int row = wn + j * 16 + lr;
                bfr[j][ks] = *(const us8*)(cB + ((row * 128 + (ks * 32 + 8 * lg) * 2)
                                                 ^ ((row & 7) << 4)));
            }

        if (more) {
            stageB_bf16(W, n0, t, w, (it + 1) * 64, &sB[cur ^ 1][0]);
            if (!f32path) stageA_bf16(Abf, m0, t, w, (it + 1) * 64, &sA[cur ^ 1][0]);
            else          stageA_f32(vx, m0, t, (it + 1) * 64, &sA[cur ^ 1][0]);
        }

#pragma unroll
        for (int i = 0; i < 4; i++)
#pragma unroll
            for (int j = 0; j < 2; j++)
#pragma unroll
                for (int ks = 0; ks < 2; ks++)
                    acc[i][j] = mfma16(af[i][ks], bfr[j][ks], acc[i][j]);

        __syncthreads();
    }

    if (z < 2) {
        ushort_t* C = z ? Ko : Qo;
        const float scale = z ? 1.0f : 0.125f * LOG2E;   // scores in log2 units
#pragma unroll
        for (int i = 0; i < 4; i++)
#pragma unroll
            for (int j = 0; j < 2; j++)
#pragma unroll
                for (int r = 0; r < 4; r++) {
                    int m = m0 + wm + i * 16 + 4 * lg + r;   // token (b*S+s)
                    int n = n0 + wn + j * 16 + lr;           // feature
                    int b = m >> 11, s = m & 2047;
                    int h = n >> 6, dh = n & 63;
                    C[(((size_t)(b * NH + h)) * SEQ + s) * DH + dh] = f2bf1(acc[i][j][r] * scale);
                }
    } else {
#pragma unroll
        for (int i = 0; i < 4; i++)
#pragma unroll
            for (int j = 0; j < 2; j++) {
                int m = m0 + wm + i * 16 + 4 * lg;           // s base; r adds 0..3
                int n = n0 + wn + j * 16 + lr;
                int b = m >> 11, s = m & 2047;
                int h = n >> 6, dh = n & 63;
                uint2 pr;
                pr.x = cvtpk(acc[i][j][0], acc[i][j][1]);
                pr.y = cvtpk(acc[i][j][2], acc[i][j][3]);
                *(uint2*)&VT[(((size_t)(b * NH + h)) * DH + dh) * SEQ + s] = pr;
            }
    }
}

// output projection: A bf16 [4096][1024] @ W0^T -> fp32 [4096][1024]
__global__ __launch_bounds__(256) void gemm_o(const ushort_t* __restrict__ A,
                                              const ushort_t* __restrict__ W,
                                              float* __restrict__ C)
{
    __shared__ ushort_t sA[2][128 * 64];
    __shared__ ushort_t sB[2][64 * 64];
    const int t = threadIdx.x, lane = t & 63, w = t >> 6;
    const int lr = lane & 15, lg = lane >> 4;
    const int wm = (w >> 1) * 64, wn = (w & 1) * 32;
    const int m0 = blockIdx.x * 128, n0 = blockIdx.y * 64;

    f32x4 acc[4][2];
    f32x4 zero = {0.f, 0.f, 0.f, 0.f};
#pragma unroll
    for (int i = 0; i < 4; i++)
#pragma unroll
        for (int j = 0; j < 2; j++) acc[i][j] = zero;

    stageA_bf16(A, m0, t, w, 0, &sA[0][0]);
    stageB_bf16(W, n0, t, w, 0, &sB[0][0]);
    __syncthreads();

    for (int it = 0; it < D_MODEL / 64; ++it) {
        const int cur = it & 1;
        const char* cA = (const char*)&sA[cur][0];
        const char* cB = (const char*)&sB[cur][0];

        us8 af[4][2], bfr[2][2];
#pragma unroll
        for (int i = 0; i < 4; i++)
#pragma unroll
            for (int ks = 0; ks < 2; ks++) {
                int row = wm + i * 16 + lr;
                af[i][ks] = *(const us8*)(cA + ((row * 128 + (ks * 32 + 8 * lg) * 2)
                                                ^ ((row & 7) << 4)));
            }
#pragma unroll
        for (int j = 0; j < 2; j++)
#pragma unroll
            for (int ks = 0; ks < 2; ks++) {
                int row = wn + j * 16 + lr;
                bfr[j][ks] = *(const us8*)(cB + ((row * 128 + (ks * 32 + 8 * lg) * 2)
                                                 ^ ((row & 7) << 4)));
            }

        if (it + 1 < D_MODEL / 64) {
            stageA_bf16(A, m0, t, w, (it + 1) * 64, &sA[cur ^ 1][0]);
            stageB_bf16(W, n0, t, w, (it + 1) * 64, &sB[cur ^ 1][0]);
        }

#pragma unroll
        for (int i = 0; i < 4; i++)
#pragma unroll
            for (int j = 0; j < 2; j++)
#pragma unroll
                for (int ks = 0; ks < 2; ks++)
                    acc[i][j] = mfma16(af[i][ks], bfr[j][ks], acc[i][j]);

        __syncthreads();
    }

#pragma unroll
    for (int i = 0; i < 4; i++)
#pragma unroll
        for (int j = 0; j < 2; j++)
#pragma unroll
            for (int r = 0; r < 4; r++) {
                int m = m0 + wm + i * 16 + 4 * lg + r;
                int n = n0 + wn + j * 16 + lr;
                C[(size_t)m * D_MODEL + n] = acc[i][j][r];
            }
}

// ---------------------------------------------------------------------------
// Flash attention, swapped-operand 32x32x16, KVBLK=64 dbuf, max-free softmax,
// permlane P-assembly (r15-r21 verified). SPLIT=true: 1024 blocks, each does
// HALF the kv range and writes UNNORMALIZED O-half (bf16) + l (fp32) --
// max-free softmax makes partials exactly additive. SPLIT=false: r21 path.
// C/D layout (HW-verified): col=lane&31, row=(r&3)+8*(r>>2)+4*(lane>>5).
// ---------------------------------------------------------------------------
template<bool SPLIT>
__global__ __launch_bounds__(256, 2) void attn_fwd(const ushort_t* __restrict__ Q,
                                                   const ushort_t* __restrict__ K,
                                                   const ushort_t* __restrict__ VT,
                                                   const float* __restrict__ mask,
                                                   const int* __restrict__ flags,
                                                   ushort_t* __restrict__ O,      // AO (non-split)
                                                   ushort_t* __restrict__ O1,     // split partials
                                                   ushort_t* __restrict__ O2,
                                                   float* __restrict__ L1,
                                                   float* __restrict__ L2)
{
    __shared__ ushort_t sK[2][64 * 64];     // 64 kv rows x 64 dh  (8 KB each)
    __shared__ ushort_t sVT[2][64 * 64];    // 64 dh rows x 64 kv

    const int t = threadIdx.x, lane = t & 63, w = t >> 6;
    const int l31 = lane & 31, lh = lane >> 5;
    const int id = blockIdx.x;
    int bh, qt, half;
    if (SPLIT) {
        // 1024 blocks: xcd = id&7 owns 4 heads; rest = qt x (head&3) x half
        const int rest = id >> 3;            // 0..127
        qt = rest & 15;
        const int hh = rest >> 4;            // 0..7
        bh = (id & 7) * 4 + (hh & 3);
        half = hh >> 2;
    } else {
        bh = (id & 7) * 4 + ((id >> 3) >> 4);
        qt = (id >> 3) & 15;
        half = 0;
    }
    const int b = bh >> 4, h = bh & 15;
    const int q = qt * 128 + w * 32 + l31;   // lane's q row
    const int kv0 = SPLIT ? half * 16 : 0;
    const int nkv = SPLIT ? 16 : 32;

    // mask-tile flags for this 128-row q block (2 flag rows ORed); bit = 64-col tile
    unsigned long long blt = __ballot(flags[(qt * 2 + lh) * 32 + l31] != 0);
    const unsigned int fl = (unsigned int)(blt | (blt >> 32));

    // Q fragments: B-operand rows = q, k(d)-slots 16*ks + 8*lh + e
    us8 qfr[4];
#pragma unroll
    for (int ks = 0; ks < 4; ks++)
        qfr[ks] = *(const us8*)(Q + ((size_t)bh * SEQ + q) * DH + ks * 16 + 8 * lh);

    f32x16 acc_o[2];
#pragma unroll
    for (int d = 0; d < 2; d++)
#pragma unroll
        for (int r = 0; r < 16; r++) acc_o[d][r] = 0.f;
    float acc_l = 0.f;

    const ushort_t* Kb = K + (size_t)bh * SEQ * DH;
    const ushort_t* Vb = VT + (size_t)bh * DH * SEQ;

    // hoisted per-thread staging source pointers (advance by const per tile)
    const ushort_t* kp[2];
    const ushort_t* vp[2];
#pragma unroll
    for (int r = 0; r < 2; r++) {
        int j = r * 256 + t;                 // 512 chunks of 16B per tensor
        int row = j >> 3, cc = (j & 7) ^ (row & 7);
        kp[r] = Kb + (size_t)row * DH + cc * 8;
        vp[r] = Vb + (size_t)row * SEQ + cc * 8;
    }

#define STAGE(kvt_, buf_)                                                     \
    {                                                                         \
        _Pragma("unroll")                                                     \
        for (int r = 0; r < 2; r++)                                           \
            gload16(kp[r] + (size_t)(kvt_) * (64 * DH),                       \
                    &sK[buf_][(r * 256 + w * 64) * 8]);                       \
        _Pragma("unroll")                                                     \
        for (int r = 0; r < 2; r++)                                           \
            gload16(vp[r] + (size_t)(kvt_) * 64,                              \
                    &sVT[buf_][(r * 256 + w * 64) * 8]);                      \
    }

    STAGE(kv0, 0);
    __syncthreads();

    for (int it = 0; it < nkv; ++it) {
        const int kvt = kv0 + it;
        const int cur = it & 1;
        const char* cK = (const char*)sK[cur];
        const char* cV = (const char*)sVT[cur];

        // ---- S = K Q^T: sacc[kb][r] = S[kcol=kb*32+crow(r,lh)][q] ----
        f32x16 sacc[2];
#pragma unroll
        for (int kb = 0; kb < 2; kb++)
#pragma unroll
            for (int r = 0; r < 16; r++) sacc[kb][r] = 0.f;
        __builtin_amdgcn_s_setprio(1);
#pragma unroll
        for (int ks = 0; ks < 4; ks++)
#pragma unroll
            for (int kb = 0; kb < 2; kb++) {
                int row = kb * 32 + l31;
                int by = (row * 128 + (ks * 16 + 8 * lh) * 2) ^ ((row & 7) << 4);
                us8 kf = *(const us8*)(cK + by);
                sacc[kb] = mfma32(kf, qfr[ks], sacc[kb]);
            }
        __builtin_amdgcn_s_setprio(0);

        // ---- V-frag reads (last ds_reads of this tile) ----
        us8 vf[4][2];
#pragma unroll
        for (int ks = 0; ks < 4; ks++)
#pragma unroll
            for (int dblk = 0; dblk < 2; dblk++) {
                int row = dblk * 32 + l31;
                int by = (row * 128 + (ks * 16 + 8 * lh) * 2) ^ ((row & 7) << 4);
                vf[ks][dblk] = *(const us8*)(cV + by);
            }

        // ---- stage next tile; loads hide under softmax + PV ----
        if (it + 1 < nkv) STAGE(kvt + 1, cur ^ 1);

        // ---- additive mask (log2; skipped when 64-col tile all-zero) ----
        if ((fl >> kvt) & 1u) {
#pragma unroll
            for (int kb = 0; kb < 2; kb++)
#pragma unroll
                for (int r = 0; r < 16; r++) {
                    int kcol = kb * 32 + (r & 3) + 8 * (r >> 2) + 4 * lh;
                    sacc[kb][r] += mask[(size_t)q * SEQ + kvt * 64 + kcol] * LOG2E;
                }
        }

        // ---- P = exp2(S) in place (max-free); l partial sum ----
        float rs = 0.f;
#pragma unroll
        for (int kb = 0; kb < 2; kb++)
#pragma unroll
            for (int r = 0; r < 16; r++) {
                float p = exp2_fast(sacc[kb][r]);
                sacc[kb][r] = p;
                rs += p;
            }
        rs += __shfl_xor(rs, 32);
        acc_l += rs;

        // ---- PV: P B-frags via cvt_pk + permlane32_swap (verified r12) ----
        __builtin_amdgcn_s_setprio(1);
#pragma unroll
        for (int ks = 0; ks < 4; ks++) {
            const int kb = ks >> 1, u = ks & 1;
            unsigned int W0 = cvtpk(sacc[kb][8 * u + 0], sacc[kb][8 * u + 1]);
            unsigned int W1 = cvtpk(sacc[kb][8 * u + 2], sacc[kb][8 * u + 3]);
            unsigned int W2 = cvtpk(sacc[kb][8 * u + 4], sacc[kb][8 * u + 5]);
            unsigned int W3 = cvtpk(sacc[kb][8 * u + 6], sacc[kb][8 * u + 7]);
            asm("v_permlane32_swap_b32 %0, %1" : "+v"(W0), "+v"(W2));
            asm("v_permlane32_swap_b32 %0, %1" : "+v"(W1), "+v"(W3));
            u32x4 pw;
            pw[0] = W0; pw[1] = W1; pw[2] = W2; pw[3] = W3;
            us8 pf = __builtin_bit_cast(us8, pw);
#pragma unroll
            for (int dblk = 0; dblk < 2; dblk++)
                acc_o[dblk] = mfma32(vf[ks][dblk], pf, acc_o[dblk]);
        }
        __builtin_amdgcn_s_setprio(0);

        __syncthreads();   // drains stage(kvt+1); protects buf reuse
    }

    // ---- epilogue ----
    if (SPLIT) {
        // unnormalized partial O (bf16) + l (fp32); combine sums halves
        ushort_t* Op = half ? O2 : O1;
        ushort_t* Orow = Op + ((size_t)(b * SEQ) + q) * D_MODEL + h * DH;
#pragma unroll
        for (int dblk = 0; dblk < 2; dblk++)
#pragma unroll
            for (int g = 0; g < 4; g++) {
                unsigned int lo = cvtpk(acc_o[dblk][4 * g + 0], acc_o[dblk][4 * g + 1]);
                unsigned int hi = cvtpk(acc_o[dblk][4 * g + 2], acc_o[dblk][4 * g + 3]);
                uint2 pr; pr.x = lo; pr.y = hi;
                *(uint2*)(Orow + dblk * 32 + 8 * g + 4 * lh) = pr;
            }
        if (lh == 0) {
            float* Lp = half ? L2 : L1;
            Lp[((size_t)(b * SEQ) + q) * NH + h] = acc_l;
        }
    } else {
        float inv = 1.f / acc_l;
        ushort_t* Orow = O + ((size_t)(b * SEQ) + q) * D_MODEL + h * DH;
#pragma unroll
        for (int dblk = 0; dblk < 2; dblk++)
#pragma unroll
            for (int g = 0; g < 4; g++) {
                unsigned int lo = cvtpk(acc_o[dblk][4 * g + 0] * inv,
                                        acc_o[dblk][4 * g + 1] * inv);
                unsigned int hi = cvtpk(acc_o[dblk][4 * g + 2] * inv,
                                        acc_o[dblk][4 * g + 3] * inv);
                uint2 pr; pr.x = lo; pr.y = hi;
                *(uint2*)(Orow + dblk * 32 + 8 * g + 4 * lh) = pr;
            }
    }
#undef STAGE
}

// ---------------------------------------------------------------------------
extern "C" void kernel_launch(void* const* d_in, const int* in_sizes, int n_in,
                              void* d_out, int out_size, void* d_ws, size_t ws_size,
                              hipStream_t stream)
{
    const float* qx   = (const float*)d_in[0];
    const float* kx   = (const float*)d_in[1];
    const float* vx   = (const float*)d_in[2];
    const float* mask = (const float*)d_in[3];
    const float* wq   = (const float*)d_in[4];
    const float* wk   = (const float*)d_in[5];
    const float* wv   = (const float*)d_in[6];
    const float* w0   = (const float*)d_in[7];
    float* out = (float*)d_out;

    char* ws = (char*)d_ws;
    const size_t MB = 1024 * 1024;
    const size_t KB = 1024;
    ushort_t* Aq = (ushort_t*)(ws);                 // qx bf16, 8 MB; dead after
    ushort_t* O1p = (ushort_t*)(ws);                //   gemm_qkv -> O1 partial
    ushort_t* Ak = (ushort_t*)(ws + 8 * MB);        // kx bf16, 8 MB; dead after
    ushort_t* AO = (ushort_t*)(ws + 8 * MB);        //   gemm_qkv -> AO
    ushort_t* Wq = (ushort_t*)(ws + 16 * MB);       // 2 MB each
    ushort_t* Wk = (ushort_t*)(ws + 18 * MB);
    ushort_t* Wv = (ushort_t*)(ws + 20 * MB);
    ushort_t* W0 = (ushort_t*)(ws + 22 * MB);
    ushort_t* VT = (ushort_t*)(ws + 24 * MB);       // [B,H,Dh,S] bf16, 8 MB

    // ws probe (>=41 MB proven in r21 via gemm_qkv speedup): Av slot doubles
    // as O2 partial after gemm_qkv; flags + l buffers at 40 MB.
    const bool bigws = (ws_size >= 41 * MB);
    ushort_t* Av  = bigws ? (ushort_t*)(ws + 32 * MB) : nullptr;  // 8 MB
    ushort_t* O2p = (ushort_t*)(ws + 32 * MB);
    int* flags    = (int*)(ws + (bigws ? 40 * MB : 32 * MB));     // 4 KB
    float* L1     = (float*)(ws + 40 * MB + 64 * KB);             // 256 KB
    float* L2     = (float*)(ws + 40 * MB + 384 * KB);            // 256 KB

    // Q and K (bf16, [B,H,S,Dh]) live in d_out until attn consumes them
    ushort_t* Qb = (ushort_t*)d_out;
    ushort_t* Kb = (ushort_t*)d_out + 4 * MB;       // +8 MB bytes

    hipMemsetAsync(flags, 0, 32 * 32 * sizeof(int), stream);
    mask_flags<<<dim3(32, 32), 256, 0, stream>>>(mask, flags);

    // weights fp32 -> bf16 (one fused launch)
    conv_multi<<<dim3(256, 1, 4), 256, 0, stream>>>(wq, Wq, wk, Wk, wv, Wv, w0, W0, 262144);
    // inputs fp32 -> bf16 (qx, kx always; vx too when workspace allows)
    conv_multi<<<dim3(1024, 1, bigws ? 3 : 2), 256, 0, stream>>>(
        qx, Aq, kx, Ak, vx, bigws ? Av : Aq, qx, Aq, 1048576);

    // fused QKV projections: all-bf16 when bigws, else z=2 fp32 in-kernel
    gemm_qkv<<<dim3(32, 16, 3), 256, 0, stream>>>(Aq, Ak, Av, vx,
                                                  Wq, Wk, Wv, Qb, Kb, VT);

    if (bigws) {
        // KV-split attention: 2x occupancy; partials exactly additive
        attn_fwd<true><<<1024, 256, 0, stream>>>(Qb, Kb, VT, mask, flags,
                                                 nullptr, O1p, O2p, L1, L2);
        combine<<<2048, 256, 0, stream>>>(O1p, O2p, L1, L2, AO);
    } else {
        attn_fwd<false><<<512, 256, 0, stream>>>(Qb, Kb, VT, mask, flags,
                                                 AO, nullptr, nullptr, nullptr, nullptr);
    }

    gemm_o<<<dim3(32, 16), 256, 0, stream>>>(AO, W0, out);
}

// Round 24
// 123.029 us; speedup vs baseline: 1.0826x; 1.0826x over previous
//
#include <hip/hip_runtime.h>
#include <hip/hip_bf16.h>
#include <stdint.h>

#define D_MODEL 1024
#define NH 16
#define DH 64
#define SEQ 2048
#define MROWS 4096   // B*S
#define LOG2E 1.44269504088896340736f

typedef unsigned short ushort_t;
typedef __attribute__((ext_vector_type(4))) float f32x4;
typedef __attribute__((ext_vector_type(16))) float f32x16;
typedef __attribute__((ext_vector_type(4))) unsigned short us4;
typedef __attribute__((ext_vector_type(8))) unsigned short us8;
typedef __attribute__((ext_vector_type(4))) unsigned int u32x4;
typedef __attribute__((ext_vector_type(8))) __bf16 bf16x8;

__device__ __forceinline__ f32x4 mfma16(us8 a, us8 b, f32x4 c) {
    return __builtin_amdgcn_mfma_f32_16x16x32_bf16(
        __builtin_bit_cast(bf16x8, a), __builtin_bit_cast(bf16x8, b), c, 0, 0, 0);
}
__device__ __forceinline__ f32x16 mfma32(us8 a, us8 b, f32x16 c) {
    return __builtin_amdgcn_mfma_f32_32x32x16_bf16(
        __builtin_bit_cast(bf16x8, a), __builtin_bit_cast(bf16x8, b), c, 0, 0, 0);
}

// packed f32x2 -> bf16x2, RNE (verified == manual RNE in rounds 7-21)
__device__ __forceinline__ unsigned int cvtpk(float lo, float hi) {
    unsigned int r;
    asm("v_cvt_pk_bf16_f32 %0, %1, %2" : "=v"(r) : "v"(lo), "v"(hi));
    return r;
}
// single f32 -> bf16 (1 VALU op)
__device__ __forceinline__ ushort_t f2bf1(float f) {
    return (ushort_t)(cvtpk(f, f) & 0xffffu);
}

__device__ __forceinline__ float exp2_fast(float x) {
#if __has_builtin(__builtin_amdgcn_exp2f)
    return __builtin_amdgcn_exp2f(x);
#else
    float r; asm("v_exp_f32 %0, %1" : "=v"(r) : "v"(x)); return r;
#endif
}

// async global->LDS, 16B per lane; LDS base wave-uniform, lane i at base+i*16
__device__ __forceinline__ void gload16(const void* g, void* l) {
    __builtin_amdgcn_global_load_lds(
        (const __attribute__((address_space(1))) void*)g,
        (__attribute__((address_space(3))) void*)l, 16, 0, 0);
}

// ---------------------------------------------------------------------------
// single fused fp32 -> bf16 conversion for ALL tensors: z in [0,7) picks
// (src,dst); z<4 = weights (262144 float4), z>=4 = inputs (1048576 float4).
// Grid-stride absorbs the size difference. One launch replaces two.
// ---------------------------------------------------------------------------
__global__ __launch_bounds__(256) void conv_all(
    const float* __restrict__ s0, ushort_t* __restrict__ d0,
    const float* __restrict__ s1, ushort_t* __restrict__ d1,
    const float* __restrict__ s2, ushort_t* __restrict__ d2,
    const float* __restrict__ s3, ushort_t* __restrict__ d3,
    const float* __restrict__ s4, ushort_t* __restrict__ d4,
    const float* __restrict__ s5, ushort_t* __restrict__ d5,
    const float* __restrict__ s6, ushort_t* __restrict__ d6)
{
    int z = blockIdx.z;
    const float* s = z == 0 ? s0 : z == 1 ? s1 : z == 2 ? s2 : z == 3 ? s3
                   : z == 4 ? s4 : z == 5 ? s5 : s6;
    ushort_t* d    = z == 0 ? d0 : z == 1 ? d1 : z == 2 ? d2 : z == 3 ? d3
                   : z == 4 ? d4 : z == 5 ? d5 : d6;
    const int n4 = (z < 4) ? 262144 : 1048576;
    int i = blockIdx.x * 256 + threadIdx.x;
    int stride = gridDim.x * 256;
    for (; i < n4; i += stride) {
        float4 v = ((const float4*)s)[i];
        uint2 pr;
        pr.x = cvtpk(v.x, v.y);
        pr.y = cvtpk(v.z, v.w);
        ((uint2*)d)[i] = pr;
    }
}

// ---------------------------------------------------------------------------
// mask tile flags at 64x64 granularity; LDS wave-OR reduce + plain store
// (no memset / atomics -> one fewer dispatch)
// ---------------------------------------------------------------------------
__global__ __launch_bounds__(256) void mask_flags(const float* __restrict__ mask,
                                                  int* __restrict__ flags)
{
    __shared__ int s[4];
    int qt = blockIdx.x, kt = blockIdx.y;
    int t = threadIdx.x;
    bool nz = false;
#pragma unroll
    for (int i = 0; i < 4; i++) {
        int idx = t + i * 256;               // 1024 float4: 64 rows x 16
        int row = idx >> 4, c4 = (idx & 15) * 4;
        float4 v = *(const float4*)(mask + (size_t)(qt * 64 + row) * SEQ + kt * 64 + c4);
        nz |= (v.x != 0.f) | (v.y != 0.f) | (v.z != 0.f) | (v.w != 0.f);
    }
    int wa = (int)(__any((int)nz) != 0);
    if ((t & 63) == 0) s[t >> 6] = wa;
    __syncthreads();
    if (t == 0) flags[qt * 32 + kt] = s[0] | s[1] | s[2] | s[3];
}

// ---------------------------------------------------------------------------
// GEMM staging, XOR-SWIZZLED LDS (r18-verified: conflicts 14.16M -> 0)
// ---------------------------------------------------------------------------
__device__ __forceinline__ void stageB_bf16(const ushort_t* __restrict__ B,
                                            int n0, int t, int w, int k0,
                                            ushort_t* sB)
{
#pragma unroll
    for (int r = 0; r < 2; r++) {
        int chunk = r * 256 + t;
        int row = chunk >> 3, cc = (chunk & 7) ^ (row & 7);
        gload16(B + (size_t)(n0 + row) * D_MODEL + k0 + cc * 8,
                &sB[(r * 256 + w * 64) * 8]);
    }
}

__device__ __forceinline__ void stageA_bf16(const ushort_t* __restrict__ A,
                                            int m0, int t, int w, int k0,
                                            ushort_t* sA)
{
#pragma unroll
    for (int r = 0; r < 4; r++) {
        int chunk = r * 256 + t;                   // 1024 chunks of 8 bf16
        int row = chunk >> 3, cc = (chunk & 7) ^ (row & 7);
        gload16(A + (size_t)(m0 + row) * D_MODEL + k0 + cc * 8,
                &sA[(r * 256 + w * 64) * 8]);
    }
}

__device__ __forceinline__ void stageA_f32(const float* __restrict__ A,
                                           int m0, int t, int k0,
                                           ushort_t* sA)
{
#pragma unroll
    for (int r = 0; r < 4; r++) {
        int chunk = r * 256 + t;
        int row = chunk >> 3, c = chunk & 7;
        const float* src = A + (size_t)(m0 + row) * D_MODEL + k0 + c * 8;
        float4 v0 = *(const float4*)src;
        float4 v1 = *(const float4*)(src + 4);
        u32x4 pw;
        pw[0] = cvtpk(v0.x, v0.y); pw[1] = cvtpk(v0.z, v0.w);
        pw[2] = cvtpk(v1.x, v1.y); pw[3] = cvtpk(v1.z, v1.w);
        int by = (row * 128 + c * 16) ^ ((row & 7) << 4);   // swizzled dest
        *(u32x4*)((char*)sA + by) = pw;
    }
}

// ---------------------------------------------------------------------------
// fused QKV projection (r20/21-verified): z=0 Aq->Qb (scaled), z=1 Ak->Kb,
// z=2 Av (or fp32 vx fallback) -> VT. 2-phase dbuf, swizzled LDS.
// ---------------------------------------------------------------------------
__global__ __launch_bounds__(256) void gemm_qkv(const ushort_t* __restrict__ Aq,
                                                const ushort_t* __restrict__ Ak,
                                                const ushort_t* __restrict__ Av,
                                                const float* __restrict__ vx,
                                                const ushort_t* __restrict__ Wq,
                                                const ushort_t* __restrict__ Wk,
                                                const ushort_t* __restrict__ Wv,
                                                ushort_t* __restrict__ Qo,
                                                ushort_t* __restrict__ Ko,
                                                ushort_t* __restrict__ VT)
{
    __shared__ ushort_t sA[2][128 * 64];
    __shared__ ushort_t sB[2][64 * 64];
    const int z = blockIdx.z;
    const ushort_t* Abf = z == 0 ? Aq : z == 1 ? Ak : Av;
    const ushort_t* W = z == 0 ? Wq : z == 1 ? Wk : Wv;
    const bool f32path = (z == 2) && (Av == nullptr);
    const int t = threadIdx.x, lane = t & 63, w = t >> 6;
    const int lr = lane & 15, lg = lane >> 4;
    const int wm = (w >> 1) * 64, wn = (w & 1) * 32;
    const int m0 = blockIdx.x * 128, n0 = blockIdx.y * 64;

    f32x4 acc[4][2];
    f32x4 zero = {0.f, 0.f, 0.f, 0.f};
#pragma unroll
    for (int i = 0; i < 4; i++)
#pragma unroll
        for (int j = 0; j < 2; j++) acc[i][j] = zero;

    stageB_bf16(W, n0, t, w, 0, &sB[0][0]);
    if (!f32path) stageA_bf16(Abf, m0, t, w, 0, &sA[0][0]);
    else          stageA_f32(vx, m0, t, 0, &sA[0][0]);
    __syncthreads();

    for (int it = 0; it < D_MODEL / 64; ++it) {
        const int cur = it & 1;
        const char* cA = (const char*)&sA[cur][0];
        const char* cB = (const char*)&sB[cur][0];
        const bool more = (it + 1 < D_MODEL / 64);

        us8 af[4][2], bfr[2][2];
#pragma unroll
        for (int i = 0; i < 4; i++)
#pragma unroll
            for (int ks = 0; ks < 2; ks++) {
                int row = wm + i * 16 + lr;
                af[i][ks] = *(const us8*)(cA + ((row * 128 + (ks * 32 + 8 * lg) * 2)
                                                ^ ((row & 7) << 4)));
            }
#pragma unroll
        for (int j = 0; j < 2; j++)
#pragma unroll
            for (int ks = 0; ks < 2; ks++) {
                int row = wn + j * 16 + lr;
                bfr[j][ks] = *(const us8*)(cB + ((row * 128 + (ks * 32 + 8 * lg) * 2)
                                                 ^ ((row & 7) << 4)));
            }

        if (more) {
            stageB_bf16(W, n0, t, w, (it + 1) * 64, &sB[cur ^ 1][0]);
            if (!f32path) stageA_bf16(Abf, m0, t, w, (it + 1) * 64, &sA[cur ^ 1][0]);
            else          stageA_f32(vx, m0, t, (it + 1) * 64, &sA[cur ^ 1][0]);
        }

#pragma unroll
        for (int i = 0; i < 4; i++)
#pragma unroll
            for (int j = 0; j < 2; j++)
#pragma unroll
                for (int ks = 0; ks < 2; ks++)
                    acc[i][j] = mfma16(af[i][ks], bfr[j][ks], acc[i][j]);

        __syncthreads();
    }

    if (z < 2) {
        ushort_t* C = z ? Ko : Qo;
        const float scale = z ? 1.0f : 0.125f * LOG2E;   // scores in log2 units
#pragma unroll
        for (int i = 0; i < 4; i++)
#pragma unroll
            for (int j = 0; j < 2; j++)
#pragma unroll
                for (int r = 0; r < 4; r++) {
                    int m = m0 + wm + i * 16 + 4 * lg + r;   // token (b*S+s)
                    int n = n0 + wn + j * 16 + lr;           // feature
                    int b = m >> 11, s = m & 2047;
                    int h = n >> 6, dh = n & 63;
                    C[(((size_t)(b * NH + h)) * SEQ + s) * DH + dh] = f2bf1(acc[i][j][r] * scale);
                }
    } else {
#pragma unroll
        for (int i = 0; i < 4; i++)
#pragma unroll
            for (int j = 0; j < 2; j++) {
                int m = m0 + wm + i * 16 + 4 * lg;           // s base; r adds 0..3
                int n = n0 + wn + j * 16 + lr;
                int b = m >> 11, s = m & 2047;
                int h = n >> 6, dh = n & 63;
                uint2 pr;
                pr.x = cvtpk(acc[i][j][0], acc[i][j][1]);
                pr.y = cvtpk(acc[i][j][2], acc[i][j][3]);
                *(uint2*)&VT[(((size_t)(b * NH + h)) * DH + dh) * SEQ + s] = pr;
            }
    }
}

// output projection: A bf16 [4096][1024] @ W0^T -> fp32 [4096][1024]
__global__ __launch_bounds__(256) void gemm_o(const ushort_t* __restrict__ A,
                                              const ushort_t* __restrict__ W,
                                              float* __restrict__ C)
{
    __shared__ ushort_t sA[2][128 * 64];
    __shared__ ushort_t sB[2][64 * 64];
    const int t = threadIdx.x, lane = t & 63, w = t >> 6;
    const int lr = lane & 15, lg = lane >> 4;
    const int wm = (w >> 1) * 64, wn = (w & 1) * 32;
    const int m0 = blockIdx.x * 128, n0 = blockIdx.y * 64;

    f32x4 acc[4][2];
    f32x4 zero = {0.f, 0.f, 0.f, 0.f};
#pragma unroll
    for (int i = 0; i < 4; i++)
#pragma unroll
        for (int j = 0; j < 2; j++) acc[i][j] = zero;

    stageA_bf16(A, m0, t, w, 0, &sA[0][0]);
    stageB_bf16(W, n0, t, w, 0, &sB[0][0]);
    __syncthreads();

    for (int it = 0; it < D_MODEL / 64; ++it) {
        const int cur = it & 1;
        const char* cA = (const char*)&sA[cur][0];
        const char* cB = (const char*)&sB[cur][0];

        us8 af[4][2], bfr[2][2];
#pragma unroll
        for (int i = 0; i < 4; i++)
#pragma unroll
            for (int ks = 0; ks < 2; ks++) {
                int row = wm + i * 16 + lr;
                af[i][ks] = *(const us8*)(cA + ((row * 128 + (ks * 32 + 8 * lg) * 2)
                                                ^ ((row & 7) << 4)));
            }
#pragma unroll
        for (int j = 0; j < 2; j++)
#pragma unroll
            for (int ks = 0; ks < 2; ks++) {
                int row = wn + j * 16 + lr;
                bfr[j][ks] = *(const us8*)(cB + ((row * 128 + (ks * 32 + 8 * lg) * 2)
                                                 ^ ((row & 7) << 4)));
            }

        if (it + 1 < D_MODEL / 64) {
            stageA_bf16(A, m0, t, w, (it + 1) * 64, &sA[cur ^ 1][0]);
            stageB_bf16(W, n0, t, w, (it + 1) * 64, &sB[cur ^ 1][0]);
        }

#pragma unroll
        for (int i = 0; i < 4; i++)
#pragma unroll
            for (int j = 0; j < 2; j++)
#pragma unroll
                for (int ks = 0; ks < 2; ks++)
                    acc[i][j] = mfma16(af[i][ks], bfr[j][ks], acc[i][j]);

        __syncthreads();
    }

#pragma unroll
    for (int i = 0; i < 4; i++)
#pragma unroll
        for (int j = 0; j < 2; j++)
#pragma unroll
            for (int r = 0; r < 4; r++) {
                int m = m0 + wm + i * 16 + 4 * lg + r;
                int n = n0 + wn + j * 16 + lr;
                C[(size_t)m * D_MODEL + n] = acc[i][j][r];
            }
}

// ---------------------------------------------------------------------------
// Flash attention (r15/r21 champion, single-pass): swapped-operand 32x32x16,
// KVBLK=64 dbuf, 32 KB LDS, launch_bounds(256,2), max-free softmax, permlane
// P-assembly, l on VALU, XCD swizzle, hoisted stage ptrs. r23 established
// this is a per-CU throughput floor (KV-split gave 0 at +8us cost).
// C/D layout (HW-verified): col=lane&31, row=(r&3)+8*(r>>2)+4*(lane>>5).
// ---------------------------------------------------------------------------
__global__ __launch_bounds__(256, 2) void attn_fwd(const ushort_t* __restrict__ Q,
                                                   const ushort_t* __restrict__ K,
                                                   const ushort_t* __restrict__ VT,
                                                   const float* __restrict__ mask,
                                                   const int* __restrict__ flags,
                                                   ushort_t* __restrict__ O)
{
    __shared__ ushort_t sK[2][64 * 64];     // 64 kv rows x 64 dh  (8 KB each)
    __shared__ ushort_t sVT[2][64 * 64];    // 64 dh rows x 64 kv

    const int t = threadIdx.x, lane = t & 63, w = t >> 6;
    const int l31 = lane & 31, lh = lane >> 5;
    const int id = blockIdx.x;
    const int bh = (id & 7) * 4 + ((id >> 3) >> 4);   // XCD-contiguous heads
    const int qt = (id >> 3) & 15;
    const int b = bh >> 4, h = bh & 15;
    const int q = qt * 128 + w * 32 + l31;   // lane's q row

    // mask-tile flags for this 128-row q block (2 flag rows ORed); bit = 64-col tile
    unsigned long long blt = __ballot(flags[(qt * 2 + lh) * 32 + l31] != 0);
    const unsigned int fl = (unsigned int)(blt | (blt >> 32));

    // Q fragments: B-operand rows = q, k(d)-slots 16*ks + 8*lh + e
    us8 qfr[4];
#pragma unroll
    for (int ks = 0; ks < 4; ks++)
        qfr[ks] = *(const us8*)(Q + ((size_t)bh * SEQ + q) * DH + ks * 16 + 8 * lh);

    f32x16 acc_o[2];
#pragma unroll
    for (int d = 0; d < 2; d++)
#pragma unroll
        for (int r = 0; r < 16; r++) acc_o[d][r] = 0.f;
    float acc_l = 0.f;

    const ushort_t* Kb = K + (size_t)bh * SEQ * DH;
    const ushort_t* Vb = VT + (size_t)bh * DH * SEQ;

    // hoisted per-thread staging source pointers (advance by const per tile)
    const ushort_t* kp[2];
    const ushort_t* vp[2];
#pragma unroll
    for (int r = 0; r < 2; r++) {
        int j = r * 256 + t;                 // 512 chunks of 16B per tensor
        int row = j >> 3, cc = (j & 7) ^ (row & 7);
        kp[r] = Kb + (size_t)row * DH + cc * 8;
        vp[r] = Vb + (size_t)row * SEQ + cc * 8;
    }

#define STAGE(kvt_, buf_)                                                     \
    {                                                                         \
        _Pragma("unroll")                                                     \
        for (int r = 0; r < 2; r++)                                           \
            gload16(kp[r] + (size_t)(kvt_) * (64 * DH),                       \
                    &sK[buf_][(r * 256 + w * 64) * 8]);                       \
        _Pragma("unroll")                                                     \
        for (int r = 0; r < 2; r++)                                           \
            gload16(vp[r] + (size_t)(kvt_) * 64,                              \
                    &sVT[buf_][(r * 256 + w * 64) * 8]);                      \
    }

    STAGE(0, 0);
    __syncthreads();

    for (int kvt = 0; kvt < SEQ / 64; ++kvt) {
        const int cur = kvt & 1;
        const char* cK = (const char*)sK[cur];
        const char* cV = (const char*)sVT[cur];

        // ---- S = K Q^T: sacc[kb][r] = S[kcol=kb*32+crow(r,lh)][q] ----
        f32x16 sacc[2];
#pragma unroll
        for (int kb = 0; kb < 2; kb++)
#pragma unroll
            for (int r = 0; r < 16; r++) sacc[kb][r] = 0.f;
        __builtin_amdgcn_s_setprio(1);
#pragma unroll
        for (int ks = 0; ks < 4; ks++)
#pragma unroll
            for (int kb = 0; kb < 2; kb++) {
                int row = kb * 32 + l31;
                int by = (row * 128 + (ks * 16 + 8 * lh) * 2) ^ ((row & 7) << 4);
                us8 kf = *(const us8*)(cK + by);
                sacc[kb] = mfma32(kf, qfr[ks], sacc[kb]);
            }
        __builtin_amdgcn_s_setprio(0);

        // ---- V-frag reads (last ds_reads of this tile) ----
        us8 vf[4][2];
#pragma unroll
        for (int ks = 0; ks < 4; ks++)
#pragma unroll
            for (int dblk = 0; dblk < 2; dblk++) {
                int row = dblk * 32 + l31;
                int by = (row * 128 + (ks * 16 + 8 * lh) * 2) ^ ((row & 7) << 4);
                vf[ks][dblk] = *(const us8*)(cV + by);
            }

        // ---- stage next tile; loads hide under softmax + PV ----
        if (kvt + 1 < SEQ / 64) STAGE(kvt + 1, cur ^ 1);

        // ---- additive mask (log2; skipped when 64-col tile all-zero) ----
        if ((fl >> kvt) & 1u) {
#pragma unroll
            for (int kb = 0; kb < 2; kb++)
#pragma unroll
                for (int r = 0; r < 16; r++) {
                    int kcol = kb * 32 + (r & 3) + 8 * (r >> 2) + 4 * lh;
                    sacc[kb][r] += mask[(size_t)q * SEQ + kvt * 64 + kcol] * LOG2E;
                }
        }

        // ---- P = exp2(S) in place (max-free); l partial sum ----
        float rs = 0.f;
#pragma unroll
        for (int kb = 0; kb < 2; kb++)
#pragma unroll
            for (int r = 0; r < 16; r++) {
                float p = exp2_fast(sacc[kb][r]);
                sacc[kb][r] = p;
                rs += p;
            }
        rs += __shfl_xor(rs, 32);
        acc_l += rs;

        // ---- PV: P B-frags via cvt_pk + permlane32_swap (verified r12) ----
        __builtin_amdgcn_s_setprio(1);
#pragma unroll
        for (int ks = 0; ks < 4; ks++) {
            const int kb = ks >> 1, u = ks & 1;
            unsigned int W0 = cvtpk(sacc[kb][8 * u + 0], sacc[kb][8 * u + 1]);
            unsigned int W1 = cvtpk(sacc[kb][8 * u + 2], sacc[kb][8 * u + 3]);
            unsigned int W2 = cvtpk(sacc[kb][8 * u + 4], sacc[kb][8 * u + 5]);
            unsigned int W3 = cvtpk(sacc[kb][8 * u + 6], sacc[kb][8 * u + 7]);
            asm("v_permlane32_swap_b32 %0, %1" : "+v"(W0), "+v"(W2));
            asm("v_permlane32_swap_b32 %0, %1" : "+v"(W1), "+v"(W3));
            u32x4 pw;
            pw[0] = W0; pw[1] = W1; pw[2] = W2; pw[3] = W3;
            us8 pf = __builtin_bit_cast(us8, pw);
#pragma unroll
            for (int dblk = 0; dblk < 2; dblk++)
                acc_o[dblk] = mfma32(vf[ks][dblk], pf, acc_o[dblk]);
        }
        __builtin_amdgcn_s_setprio(0);

        __syncthreads();   // drains stage(kvt+1); protects buf reuse
    }

    // ---- normalize + write [B*S][D] bf16 (d = dblk*32 + 8g + 4lh + 0..3) ----
    float inv = 1.f / acc_l;
    ushort_t* Orow = O + ((size_t)(b * SEQ) + q) * D_MODEL + h * DH;
#pragma unroll
    for (int dblk = 0; dblk < 2; dblk++)
#pragma unroll
        for (int g = 0; g < 4; g++) {
            unsigned int lo = cvtpk(acc_o[dblk][4 * g + 0] * inv,
                                    acc_o[dblk][4 * g + 1] * inv);
            unsigned int hi = cvtpk(acc_o[dblk][4 * g + 2] * inv,
                                    acc_o[dblk][4 * g + 3] * inv);
            uint2 pr; pr.x = lo; pr.y = hi;
            *(uint2*)(Orow + dblk * 32 + 8 * g + 4 * lh) = pr;
        }
#undef STAGE
}

// ---------------------------------------------------------------------------
extern "C" void kernel_launch(void* const* d_in, const int* in_sizes, int n_in,
                              void* d_out, int out_size, void* d_ws, size_t ws_size,
                              hipStream_t stream)
{
    const float* qx   = (const float*)d_in[0];
    const float* kx   = (const float*)d_in[1];
    const float* vx   = (const float*)d_in[2];
    const float* mask = (const float*)d_in[3];
    const float* wq   = (const float*)d_in[4];
    const float* wk   = (const float*)d_in[5];
    const float* wv   = (const float*)d_in[6];
    const float* w0   = (const float*)d_in[7];
    float* out = (float*)d_out;

    char* ws = (char*)d_ws;
    const size_t MB = 1024 * 1024;
    ushort_t* Aq = (ushort_t*)(ws);                 // qx bf16, 8 MB
    ushort_t* Ak = (ushort_t*)(ws + 8 * MB);        // kx bf16, 8 MB; dead after
    ushort_t* AO = (ushort_t*)(ws + 8 * MB);        //   gemm_qkv -> AO reuses it
    ushort_t* Wq = (ushort_t*)(ws + 16 * MB);       // 2 MB each
    ushort_t* Wk = (ushort_t*)(ws + 18 * MB);
    ushort_t* Wv = (ushort_t*)(ws + 20 * MB);
    ushort_t* W0 = (ushort_t*)(ws + 22 * MB);
    ushort_t* VT = (ushort_t*)(ws + 24 * MB);       // [B,H,Dh,S] bf16, 8 MB

    // ws probe (r21-proven >=41 MB available on this harness): Av enables the
    // all-bf16 gemm_qkv; fallback = r20 configuration (z=2 fp32 in-kernel).
    const bool bigws = (ws_size >= 41 * MB);
    ushort_t* Av = bigws ? (ushort_t*)(ws + 32 * MB) : nullptr;   // 8 MB
    int* flags   = (int*)(ws + (bigws ? 40 * MB : 32 * MB));      // 4 KB

    // Q and K (bf16, [B,H,S,Dh]) live in d_out until attn consumes them
    ushort_t* Qb = (ushort_t*)d_out;
    ushort_t* Kb = (ushort_t*)d_out + 4 * MB;       // +8 MB bytes

    // flags written directly by mask_flags (no memset needed)
    mask_flags<<<dim3(32, 32), 256, 0, stream>>>(mask, flags);

    // ALL fp32 -> bf16 conversions in one launch (weights + inputs)
    conv_all<<<dim3(512, 1, bigws ? 7 : 6), 256, 0, stream>>>(
        wq, Wq, wk, Wk, wv, Wv, w0, W0,
        qx, Aq, kx, Ak, vx, bigws ? Av : Aq);

    // fused QKV projections: all-bf16 when bigws, else z=2 fp32 in-kernel
    gemm_qkv<<<dim3(32, 16, 3), 256, 0, stream>>>(Aq, Ak, Av, vx,
                                                  Wq, Wk, Wv, Qb, Kb, VT);

    attn_fwd<<<512, 256, 0, stream>>>(Qb, Kb, VT, mask, flags, AO);

    gemm_o<<<dim3(32, 16), 256, 0, stream>>>(AO, W0, out);
}

// Round 25
// 122.578 us; speedup vs baseline: 1.0866x; 1.0037x over previous
//
#include <hip/hip_runtime.h>
#include <hip/hip_bf16.h>
#include <stdint.h>

#define D_MODEL 1024
#define NH 16
#define DH 64
#define SEQ 2048
#define MROWS 4096   // B*S
#define LOG2E 1.44269504088896340736f

typedef unsigned short ushort_t;
typedef __attribute__((ext_vector_type(4))) float f32x4;
typedef __attribute__((ext_vector_type(16))) float f32x16;
typedef __attribute__((ext_vector_type(4))) unsigned short us4;
typedef __attribute__((ext_vector_type(8))) unsigned short us8;
typedef __attribute__((ext_vector_type(4))) unsigned int u32x4;
typedef __attribute__((ext_vector_type(8))) __bf16 bf16x8;

__device__ __forceinline__ f32x4 mfma16(us8 a, us8 b, f32x4 c) {
    return __builtin_amdgcn_mfma_f32_16x16x32_bf16(
        __builtin_bit_cast(bf16x8, a), __builtin_bit_cast(bf16x8, b), c, 0, 0, 0);
}
__device__ __forceinline__ f32x16 mfma32(us8 a, us8 b, f32x16 c) {
    return __builtin_amdgcn_mfma_f32_32x32x16_bf16(
        __builtin_bit_cast(bf16x8, a), __builtin_bit_cast(bf16x8, b), c, 0, 0, 0);
}

// packed f32x2 -> bf16x2, RNE (verified == manual RNE in rounds 7-21)
__device__ __forceinline__ unsigned int cvtpk(float lo, float hi) {
    unsigned int r;
    asm("v_cvt_pk_bf16_f32 %0, %1, %2" : "=v"(r) : "v"(lo), "v"(hi));
    return r;
}
// single f32 -> bf16 (1 VALU op)
__device__ __forceinline__ ushort_t f2bf1(float f) {
    return (ushort_t)(cvtpk(f, f) & 0xffffu);
}

__device__ __forceinline__ float exp2_fast(float x) {
#if __has_builtin(__builtin_amdgcn_exp2f)
    return __builtin_amdgcn_exp2f(x);
#else
    float r; asm("v_exp_f32 %0, %1" : "=v"(r) : "v"(x)); return r;
#endif
}

// async global->LDS, 16B per lane; LDS base wave-uniform, lane i at base+i*16
__device__ __forceinline__ void gload16(const void* g, void* l) {
    __builtin_amdgcn_global_load_lds(
        (const __attribute__((address_space(1))) void*)g,
        (__attribute__((address_space(3))) void*)l, 16, 0, 0);
}

// ---------------------------------------------------------------------------
// single fused fp32 -> bf16 conversion for ALL tensors: z in [0,7) picks
// (src,dst); z<4 = weights (262144 float4), z>=4 = inputs (1048576 float4).
// Grid-stride absorbs the size difference. One launch replaces two.
// ---------------------------------------------------------------------------
__global__ __launch_bounds__(256) void conv_all(
    const float* __restrict__ s0, ushort_t* __restrict__ d0,
    const float* __restrict__ s1, ushort_t* __restrict__ d1,
    const float* __restrict__ s2, ushort_t* __restrict__ d2,
    const float* __restrict__ s3, ushort_t* __restrict__ d3,
    const float* __restrict__ s4, ushort_t* __restrict__ d4,
    const float* __restrict__ s5, ushort_t* __restrict__ d5,
    const float* __restrict__ s6, ushort_t* __restrict__ d6)
{
    int z = blockIdx.z;
    const float* s = z == 0 ? s0 : z == 1 ? s1 : z == 2 ? s2 : z == 3 ? s3
                   : z == 4 ? s4 : z == 5 ? s5 : s6;
    ushort_t* d    = z == 0 ? d0 : z == 1 ? d1 : z == 2 ? d2 : z == 3 ? d3
                   : z == 4 ? d4 : z == 5 ? d5 : d6;
    const int n4 = (z < 4) ? 262144 : 1048576;
    int i = blockIdx.x * 256 + threadIdx.x;
    int stride = gridDim.x * 256;
    for (; i < n4; i += stride) {
        float4 v = ((const float4*)s)[i];
        uint2 pr;
        pr.x = cvtpk(v.x, v.y);
        pr.y = cvtpk(v.z, v.w);
        ((uint2*)d)[i] = pr;
    }
}

// ---------------------------------------------------------------------------
// mask tile flags at 64x64 granularity; LDS wave-OR reduce + plain store
// (no memset / atomics -> one fewer dispatch)
// ---------------------------------------------------------------------------
__global__ __launch_bounds__(256) void mask_flags(const float* __restrict__ mask,
                                                  int* __restrict__ flags)
{
    __shared__ int s[4];
    int qt = blockIdx.x, kt = blockIdx.y;
    int t = threadIdx.x;
    bool nz = false;
#pragma unroll
    for (int i = 0; i < 4; i++) {
        int idx = t + i * 256;               // 1024 float4: 64 rows x 16
        int row = idx >> 4, c4 = (idx & 15) * 4;
        float4 v = *(const float4*)(mask + (size_t)(qt * 64 + row) * SEQ + kt * 64 + c4);
        nz |= (v.x != 0.f) | (v.y != 0.f) | (v.z != 0.f) | (v.w != 0.f);
    }
    int wa = (int)(__any((int)nz) != 0);
    if ((t & 63) == 0) s[t >> 6] = wa;
    __syncthreads();
    if (t == 0) flags[qt * 32 + kt] = s[0] | s[1] | s[2] | s[3];
}

// ---------------------------------------------------------------------------
// GEMM staging, XOR-SWIZZLED LDS (r18-verified: conflicts 14.16M -> 0)
// ---------------------------------------------------------------------------
__device__ __forceinline__ void stageB_bf16(const ushort_t* __restrict__ B,
                                            int n0, int t, int w, int k0,
                                            ushort_t* sB)
{
#pragma unroll
    for (int r = 0; r < 2; r++) {
        int chunk = r * 256 + t;
        int row = chunk >> 3, cc = (chunk & 7) ^ (row & 7);
        gload16(B + (size_t)(n0 + row) * D_MODEL + k0 + cc * 8,
                &sB[(r * 256 + w * 64) * 8]);
    }
}

__device__ __forceinline__ void stageA_bf16(const ushort_t* __restrict__ A,
                                            int m0, int t, int w, int k0,
                                            ushort_t* sA)
{
#pragma unroll
    for (int r = 0; r < 4; r++) {
        int chunk = r * 256 + t;                   // 1024 chunks of 8 bf16
        int row = chunk >> 3, cc = (chunk & 7) ^ (row & 7);
        gload16(A + (size_t)(m0 + row) * D_MODEL + k0 + cc * 8,
                &sA[(r * 256 + w * 64) * 8]);
    }
}

__device__ __forceinline__ void stageA_f32(const float* __restrict__ A,
                                           int m0, int t, int k0,
                                           ushort_t* sA)
{
#pragma unroll
    for (int r = 0; r < 4; r++) {
        int chunk = r * 256 + t;
        int row = chunk >> 3, c = chunk & 7;
        const float* src = A + (size_t)(m0 + row) * D_MODEL + k0 + c * 8;
        float4 v0 = *(const float4*)src;
        float4 v1 = *(const float4*)(src + 4);
        u32x4 pw;
        pw[0] = cvtpk(v0.x, v0.y); pw[1] = cvtpk(v0.z, v0.w);
        pw[2] = cvtpk(v1.x, v1.y); pw[3] = cvtpk(v1.z, v1.w);
        int by = (row * 128 + c * 16) ^ ((row & 7) << 4);   // swizzled dest
        *(u32x4*)((char*)sA + by) = pw;
    }
}

// ---------------------------------------------------------------------------
// fused QKV projection (r20/21-verified): z=0 Aq->Qb (scaled), z=1 Ak->Kb,
// z=2 Av (or fp32 vx fallback) -> VT. 2-phase dbuf, swizzled LDS.
// ---------------------------------------------------------------------------
__global__ __launch_bounds__(256) void gemm_qkv(const ushort_t* __restrict__ Aq,
                                                const ushort_t* __restrict__ Ak,
                                                const ushort_t* __restrict__ Av,
                                                const float* __restrict__ vx,
                                                const ushort_t* __restrict__ Wq,
                                                const ushort_t* __restrict__ Wk,
                                                const ushort_t* __restrict__ Wv,
                                                ushort_t* __restrict__ Qo,
                                                ushort_t* __restrict__ Ko,
                                                ushort_t* __restrict__ VT)
{
    __shared__ ushort_t sA[2][128 * 64];
    __shared__ ushort_t sB[2][64 * 64];
    const int z = blockIdx.z;
    const ushort_t* Abf = z == 0 ? Aq : z == 1 ? Ak : Av;
    const ushort_t* W = z == 0 ? Wq : z == 1 ? Wk : Wv;
    const bool f32path = (z == 2) && (Av == nullptr);
    const int t = threadIdx.x, lane = t & 63, w = t >> 6;
    const int lr = lane & 15, lg = lane >> 4;
    const int wm = (w >> 1) * 64, wn = (w & 1) * 32;
    const int m0 = blockIdx.x * 128, n0 = blockIdx.y * 64;

    f32x4 acc[4][2];
    f32x4 zero = {0.f, 0.f, 0.f, 0.f};
#pragma unroll
    for (int i = 0; i < 4; i++)
#pragma unroll
        for (int j = 0; j < 2; j++) acc[i][j] = zero;

    stageB_bf16(W, n0, t, w, 0, &sB[0][0]);
    if (!f32path) stageA_bf16(Abf, m0, t, w, 0, &sA[0][0]);
    else          stageA_f32(vx, m0, t, 0, &sA[0][0]);
    __syncthreads();

    for (int it = 0; it < D_MODEL / 64; ++it) {
        const int cur = it & 1;
        const char* cA = (const char*)&sA[cur][0];
        const char* cB = (const char*)&sB[cur][0];
        const bool more = (it + 1 < D_MODEL / 64);

        us8 af[4][2], bfr[2][2];
#pragma unroll
        for (int i = 0; i < 4; i++)
#pragma unroll
            for (int ks = 0; ks < 2; ks++) {
                int row = wm + i * 16 + lr;
                af[i][ks] = *(const us8*)(cA + ((row * 128 + (ks * 32 + 8 * lg) * 2)
                                                ^ ((row & 7) << 4)));
            }
#pragma unroll
        for (int j = 0; j < 2; j++)
#pragma unroll
            for (int ks = 0; ks < 2; ks++) {
                int row = wn + j * 16 + lr;
                bfr[j][ks] = *(const us8*)(cB + ((row * 128 + (ks * 32 + 8 * lg) * 2)
                                                 ^ ((row & 7) << 4)));
            }

        if (more) {
            stageB_bf16(W, n0, t, w, (it + 1) * 64, &sB[cur ^ 1][0]);
            if (!f32path) stageA_bf16(Abf, m0, t, w, (it + 1) * 64, &sA[cur ^ 1][0]);
            else          stageA_f32(vx, m0, t, (it + 1) * 64, &sA[cur ^ 1][0]);
        }

#pragma unroll
        for (int i = 0; i < 4; i++)
#pragma unroll
            for (int j = 0; j < 2; j++)
#pragma unroll
                for (int ks = 0; ks < 2; ks++)
                    acc[i][j] = mfma16(af[i][ks], bfr[j][ks], acc[i][j]);

        __syncthreads();
    }

    if (z < 2) {
        ushort_t* C = z ? Ko : Qo;
        const float scale = z ? 1.0f : 0.125f * LOG2E;   // scores in log2 units
#pragma unroll
        for (int i = 0; i < 4; i++)
#pragma unroll
            for (int j = 0; j < 2; j++)
#pragma unroll
                for (int r = 0; r < 4; r++) {
                    int m = m0 + wm + i * 16 + 4 * lg + r;   // token (b*S+s)
                    int n = n0 + wn + j * 16 + lr;           // feature
                    int b = m >> 11, s = m & 2047;
                    int h = n >> 6, dh = n & 63;
                    C[(((size_t)(b * NH + h)) * SEQ + s) * DH + dh] = f2bf1(acc[i][j][r] * scale);
                }
    } else {
#pragma unroll
        for (int i = 0; i < 4; i++)
#pragma unroll
            for (int j = 0; j < 2; j++) {
                int m = m0 + wm + i * 16 + 4 * lg;           // s base; r adds 0..3
                int n = n0 + wn + j * 16 + lr;
                int b = m >> 11, s = m & 2047;
                int h = n >> 6, dh = n & 63;
                uint2 pr;
                pr.x = cvtpk(acc[i][j][0], acc[i][j][1]);
                pr.y = cvtpk(acc[i][j][2], acc[i][j][3]);
                *(uint2*)&VT[(((size_t)(b * NH + h)) * DH + dh) * SEQ + s] = pr;
            }
    }
}

// output projection: A bf16 [4096][1024] @ W0^T -> fp32 [4096][1024]
__global__ __launch_bounds__(256) void gemm_o(const ushort_t* __restrict__ A,
                                              const ushort_t* __restrict__ W,
                                              float* __restrict__ C)
{
    __shared__ ushort_t sA[2][128 * 64];
    __shared__ ushort_t sB[2][64 * 64];
    const int t = threadIdx.x, lane = t & 63, w = t >> 6;
    const int lr = lane & 15, lg = lane >> 4;
    const int wm = (w >> 1) * 64, wn = (w & 1) * 32;
    const int m0 = blockIdx.x * 128, n0 = blockIdx.y * 64;

    f32x4 acc[4][2];
    f32x4 zero = {0.f, 0.f, 0.f, 0.f};
#pragma unroll
    for (int i = 0; i < 4; i++)
#pragma unroll
        for (int j = 0; j < 2; j++) acc[i][j] = zero;

    stageA_bf16(A, m0, t, w, 0, &sA[0][0]);
    stageB_bf16(W, n0, t, w, 0, &sB[0][0]);
    __syncthreads();

    for (int it = 0; it < D_MODEL / 64; ++it) {
        const int cur = it & 1;
        const char* cA = (const char*)&sA[cur][0];
        const char* cB = (const char*)&sB[cur][0];

        us8 af[4][2], bfr[2][2];
#pragma unroll
        for (int i = 0; i < 4; i++)
#pragma unroll
            for (int ks = 0; ks < 2; ks++) {
                int row = wm + i * 16 + lr;
                af[i][ks] = *(const us8*)(cA + ((row * 128 + (ks * 32 + 8 * lg) * 2)
                                                ^ ((row & 7) << 4)));
            }
#pragma unroll
        for (int j = 0; j < 2; j++)
#pragma unroll
            for (int ks = 0; ks < 2; ks++) {
                int row = wn + j * 16 + lr;
                bfr[j][ks] = *(const us8*)(cB + ((row * 128 + (ks * 32 + 8 * lg) * 2)
                                                 ^ ((row & 7) << 4)));
            }

        if (it + 1 < D_MODEL / 64) {
            stageA_bf16(A, m0, t, w, (it + 1) * 64, &sA[cur ^ 1][0]);
            stageB_bf16(W, n0, t, w, (it + 1) * 64, &sB[cur ^ 1][0]);
        }

#pragma unroll
        for (int i = 0; i < 4; i++)
#pragma unroll
            for (int j = 0; j < 2; j++)
#pragma unroll
                for (int ks = 0; ks < 2; ks++)
                    acc[i][j] = mfma16(af[i][ks], bfr[j][ks], acc[i][j]);

        __syncthreads();
    }

#pragma unroll
    for (int i = 0; i < 4; i++)
#pragma unroll
        for (int j = 0; j < 2; j++)
#pragma unroll
            for (int r = 0; r < 4; r++) {
                int m = m0 + wm + i * 16 + 4 * lg + r;
                int n = n0 + wn + j * 16 + lr;
                C[(size_t)m * D_MODEL + n] = acc[i][j][r];
            }
}

// ---------------------------------------------------------------------------
// Flash attention (r15/r21 champion, single-pass): swapped-operand 32x32x16,
// KVBLK=64 dbuf, 32 KB LDS, launch_bounds(256,2), max-free softmax, permlane
// P-assembly, l on VALU, XCD swizzle, hoisted stage ptrs. r23 established
// this is a per-CU throughput floor (KV-split gave 0 at +8us cost).
// C/D layout (HW-verified): col=lane&31, row=(r&3)+8*(r>>2)+4*(lane>>5).
// ---------------------------------------------------------------------------
__global__ __launch_bounds__(256, 2) void attn_fwd(const ushort_t* __restrict__ Q,
                                                   const ushort_t* __restrict__ K,
                                                   const ushort_t* __restrict__ VT,
                                                   const float* __restrict__ mask,
                                                   const int* __restrict__ flags,
                                                   ushort_t* __restrict__ O)
{
    __shared__ ushort_t sK[2][64 * 64];     // 64 kv rows x 64 dh  (8 KB each)
    __shared__ ushort_t sVT[2][64 * 64];    // 64 dh rows x 64 kv

    const int t = threadIdx.x, lane = t & 63, w = t >> 6;
    const int l31 = lane & 31, lh = lane >> 5;
    const int id = blockIdx.x;
    const int bh = (id & 7) * 4 + ((id >> 3) >> 4);   // XCD-contiguous heads
    const int qt = (id >> 3) & 15;
    const int b = bh >> 4, h = bh & 15;
    const int q = qt * 128 + w * 32 + l31;   // lane's q row

    // mask-tile flags for this 128-row q block (2 flag rows ORed); bit = 64-col tile
    unsigned long long blt = __ballot(flags[(qt * 2 + lh) * 32 + l31] != 0);
    const unsigned int fl = (unsigned int)(blt | (blt >> 32));

    // Q fragments: B-operand rows = q, k(d)-slots 16*ks + 8*lh + e
    us8 qfr[4];
#pragma unroll
    for (int ks = 0; ks < 4; ks++)
        qfr[ks] = *(const us8*)(Q + ((size_t)bh * SEQ + q) * DH + ks * 16 + 8 * lh);

    f32x16 acc_o[2];
#pragma unroll
    for (int d = 0; d < 2; d++)
#pragma unroll
        for (int r = 0; r < 16; r++) acc_o[d][r] = 0.f;
    float acc_l = 0.f;

    const ushort_t* Kb = K + (size_t)bh * SEQ * DH;
    const ushort_t* Vb = VT + (size_t)bh * DH * SEQ;

    // hoisted per-thread staging source pointers (advance by const per tile)
    const ushort_t* kp[2];
    const ushort_t* vp[2];
#pragma unroll
    for (int r = 0; r < 2; r++) {
        int j = r * 256 + t;                 // 512 chunks of 16B per tensor
        int row = j >> 3, cc = (j & 7) ^ (row & 7);
        kp[r] = Kb + (size_t)row * DH + cc * 8;
        vp[r] = Vb + (size_t)row * SEQ + cc * 8;
    }

#define STAGE(kvt_, buf_)                                                     \
    {                                                                         \
        _Pragma("unroll")                                                     \
        for (int r = 0; r < 2; r++)                                           \
            gload16(kp[r] + (size_t)(kvt_) * (64 * DH),                       \
                    &sK[buf_][(r * 256 + w * 64) * 8]);                       \
        _Pragma("unroll")                                                     \
        for (int r = 0; r < 2; r++)                                           \
            gload16(vp[r] + (size_t)(kvt_) * 64,                              \
                    &sVT[buf_][(r * 256 + w * 64) * 8]);                      \
    }

    STAGE(0, 0);
    __syncthreads();

    for (int kvt = 0; kvt < SEQ / 64; ++kvt) {
        const int cur = kvt & 1;
        const char* cK = (const char*)sK[cur];
        const char* cV = (const char*)sVT[cur];

        // ---- S = K Q^T: sacc[kb][r] = S[kcol=kb*32+crow(r,lh)][q] ----
        f32x16 sacc[2];
#pragma unroll
        for (int kb = 0; kb < 2; kb++)
#pragma unroll
            for (int r = 0; r < 16; r++) sacc[kb][r] = 0.f;
        __builtin_amdgcn_s_setprio(1);
#pragma unroll
        for (int ks = 0; ks < 4; ks++)
#pragma unroll
            for (int kb = 0; kb < 2; kb++) {
                int row = kb * 32 + l31;
                int by = (row * 128 + (ks * 16 + 8 * lh) * 2) ^ ((row & 7) << 4);
                us8 kf = *(const us8*)(cK + by);
                sacc[kb] = mfma32(kf, qfr[ks], sacc[kb]);
            }
        __builtin_amdgcn_s_setprio(0);

        // ---- V-frag reads (last ds_reads of this tile) ----
        us8 vf[4][2];
#pragma unroll
        for (int ks = 0; ks < 4; ks++)
#pragma unroll
            for (int dblk = 0; dblk < 2; dblk++) {
                int row = dblk * 32 + l31;
                int by = (row * 128 + (ks * 16 + 8 * lh) * 2) ^ ((row & 7) << 4);
                vf[ks][dblk] = *(const us8*)(cV + by);
            }

        // ---- stage next tile; loads hide under softmax + PV ----
        if (kvt + 1 < SEQ / 64) STAGE(kvt + 1, cur ^ 1);

        // ---- additive mask (log2; skipped when 64-col tile all-zero) ----
        if ((fl >> kvt) & 1u) {
#pragma unroll
            for (int kb = 0; kb < 2; kb++)
#pragma unroll
                for (int r = 0; r < 16; r++) {
                    int kcol = kb * 32 + (r & 3) + 8 * (r >> 2) + 4 * lh;
                    sacc[kb][r] += mask[(size_t)q * SEQ + kvt * 64 + kcol] * LOG2E;
                }
        }

        // ---- P = exp2(S) in place (max-free); l partial sum ----
        float rs = 0.f;
#pragma unroll
        for (int kb = 0; kb < 2; kb++)
#pragma unroll
            for (int r = 0; r < 16; r++) {
                float p = exp2_fast(sacc[kb][r]);
                sacc[kb][r] = p;
                rs += p;
            }
        rs += __shfl_xor(rs, 32);
        acc_l += rs;

        // ---- PV: P B-frags via cvt_pk + permlane32_swap (verified r12) ----
        __builtin_amdgcn_s_setprio(1);
#pragma unroll
        for (int ks = 0; ks < 4; ks++) {
            const int kb = ks >> 1, u = ks & 1;
            unsigned int W0 = cvtpk(sacc[kb][8 * u + 0], sacc[kb][8 * u + 1]);
            unsigned int W1 = cvtpk(sacc[kb][8 * u + 2], sacc[kb][8 * u + 3]);
            unsigned int W2 = cvtpk(sacc[kb][8 * u + 4], sacc[kb][8 * u + 5]);
            unsigned int W3 = cvtpk(sacc[kb][8 * u + 6], sacc[kb][8 * u + 7]);
            asm("v_permlane32_swap_b32 %0, %1" : "+v"(W0), "+v"(W2));
            asm("v_permlane32_swap_b32 %0, %1" : "+v"(W1), "+v"(W3));
            u32x4 pw;
            pw[0] = W0; pw[1] = W1; pw[2] = W2; pw[3] = W3;
            us8 pf = __builtin_bit_cast(us8, pw);
#pragma unroll
            for (int dblk = 0; dblk < 2; dblk++)
                acc_o[dblk] = mfma32(vf[ks][dblk], pf, acc_o[dblk]);
        }
        __builtin_amdgcn_s_setprio(0);

        __syncthreads();   // drains stage(kvt+1); protects buf reuse
    }

    // ---- normalize + write [B*S][D] bf16 (d = dblk*32 + 8g + 4lh + 0..3) ----
    float inv = 1.f / acc_l;
    ushort_t* Orow = O + ((size_t)(b * SEQ) + q) * D_MODEL + h * DH;
#pragma unroll
    for (int dblk = 0; dblk < 2; dblk++)
#pragma unroll
        for (int g = 0; g < 4; g++) {
            unsigned int lo = cvtpk(acc_o[dblk][4 * g + 0] * inv,
                                    acc_o[dblk][4 * g + 1] * inv);
            unsigned int hi = cvtpk(acc_o[dblk][4 * g + 2] * inv,
                                    acc_o[dblk][4 * g + 3] * inv);
            uint2 pr; pr.x = lo; pr.y = hi;
            *(uint2*)(Orow + dblk * 32 + 8 * g + 4 * lh) = pr;
        }
#undef STAGE
}

// ---------------------------------------------------------------------------
extern "C" void kernel_launch(void* const* d_in, const int* in_sizes, int n_in,
                              void* d_out, int out_size, void* d_ws, size_t ws_size,
                              hipStream_t stream)
{
    const float* qx   = (const float*)d_in[0];
    const float* kx   = (const float*)d_in[1];
    const float* vx   = (const float*)d_in[2];
    const float* mask = (const float*)d_in[3];
    const float* wq   = (const float*)d_in[4];
    const float* wk   = (const float*)d_in[5];
    const float* wv   = (const float*)d_in[6];
    const float* w0   = (const float*)d_in[7];
    float* out = (float*)d_out;

    char* ws = (char*)d_ws;
    const size_t MB = 1024 * 1024;
    ushort_t* Aq = (ushort_t*)(ws);                 // qx bf16, 8 MB
    ushort_t* Ak = (ushort_t*)(ws + 8 * MB);        // kx bf16, 8 MB; dead after
    ushort_t* AO = (ushort_t*)(ws + 8 * MB);        //   gemm_qkv -> AO reuses it
    ushort_t* Wq = (ushort_t*)(ws + 16 * MB);       // 2 MB each
    ushort_t* Wk = (ushort_t*)(ws + 18 * MB);
    ushort_t* Wv = (ushort_t*)(ws + 20 * MB);
    ushort_t* W0 = (ushort_t*)(ws + 22 * MB);
    ushort_t* VT = (ushort_t*)(ws + 24 * MB);       // [B,H,Dh,S] bf16, 8 MB

    // ws probe (r21-proven >=41 MB available on this harness): Av enables the
    // all-bf16 gemm_qkv; fallback = r20 configuration (z=2 fp32 in-kernel).
    const bool bigws = (ws_size >= 41 * MB);
    ushort_t* Av = bigws ? (ushort_t*)(ws + 32 * MB) : nullptr;   // 8 MB
    int* flags   = (int*)(ws + (bigws ? 40 * MB : 32 * MB));      // 4 KB

    // Q and K (bf16, [B,H,S,Dh]) live in d_out until attn consumes them
    ushort_t* Qb = (ushort_t*)d_out;
    ushort_t* Kb = (ushort_t*)d_out + 4 * MB;       // +8 MB bytes

    // flags written directly by mask_flags (no memset needed)
    mask_flags<<<dim3(32, 32), 256, 0, stream>>>(mask, flags);

    // ALL fp32 -> bf16 conversions in one launch (weights + inputs)
    conv_all<<<dim3(512, 1, bigws ? 7 : 6), 256, 0, stream>>>(
        wq, Wq, wk, Wk, wv, Wv, w0, W0,
        qx, Aq, kx, Ak, vx, bigws ? Av : Aq);

    // fused QKV projections: all-bf16 when bigws, else z=2 fp32 in-kernel
    gemm_qkv<<<dim3(32, 16, 3), 256, 0, stream>>>(Aq, Ak, Av, vx,
                                                  Wq, Wk, Wv, Qb, Kb, VT);

    attn_fwd<<<512, 256, 0, stream>>>(Qb, Kb, VT, mask, flags, AO);

    gemm_o<<<dim3(32, 16), 256, 0, stream>>>(AO, W0, out);
}

// Round 26
// 120.165 us; speedup vs baseline: 1.1084x; 1.0201x over previous
//
#include <hip/hip_runtime.h>
#include <hip/hip_bf16.h>
#include <stdint.h>

#define D_MODEL 1024
#define NH 16
#define DH 64
#define SEQ 2048
#define MROWS 4096   // B*S
#define LOG2E 1.44269504088896340736f

typedef unsigned short ushort_t;
typedef __attribute__((ext_vector_type(4))) float f32x4;
typedef __attribute__((ext_vector_type(16))) float f32x16;
typedef __attribute__((ext_vector_type(4))) unsigned short us4;
typedef __attribute__((ext_vector_type(8))) unsigned short us8;
typedef __attribute__((ext_vector_type(4))) unsigned int u32x4;
typedef __attribute__((ext_vector_type(8))) __bf16 bf16x8;

__device__ __forceinline__ f32x4 mfma16(us8 a, us8 b, f32x4 c) {
    return __builtin_amdgcn_mfma_f32_16x16x32_bf16(
        __builtin_bit_cast(bf16x8, a), __builtin_bit_cast(bf16x8, b), c, 0, 0, 0);
}
__device__ __forceinline__ f32x16 mfma32(us8 a, us8 b, f32x16 c) {
    return __builtin_amdgcn_mfma_f32_32x32x16_bf16(
        __builtin_bit_cast(bf16x8, a), __builtin_bit_cast(bf16x8, b), c, 0, 0, 0);
}

// packed f32x2 -> bf16x2, RNE (verified == manual RNE in rounds 7-25)
__device__ __forceinline__ unsigned int cvtpk(float lo, float hi) {
    unsigned int r;
    asm("v_cvt_pk_bf16_f32 %0, %1, %2" : "=v"(r) : "v"(lo), "v"(hi));
    return r;
}
// single f32 -> bf16 (1 VALU op)
__device__ __forceinline__ ushort_t f2bf1(float f) {
    return (ushort_t)(cvtpk(f, f) & 0xffffu);
}

__device__ __forceinline__ float exp2_fast(float x) {
#if __has_builtin(__builtin_amdgcn_exp2f)
    return __builtin_amdgcn_exp2f(x);
#else
    float r; asm("v_exp_f32 %0, %1" : "=v"(r) : "v"(x)); return r;
#endif
}

// async global->LDS, 16B per lane; LDS base wave-uniform, lane i at base+i*16
__device__ __forceinline__ void gload16(const void* g, void* l) {
    __builtin_amdgcn_global_load_lds(
        (const __attribute__((address_space(1))) void*)g,
        (__attribute__((address_space(3))) void*)l, 16, 0, 0);
}

// ---------------------------------------------------------------------------
// single fused prep kernel: z < nconv does fp32->bf16 conversion (z<4 weights
// 262144 float4, else inputs 1048576 float4); z == nconv computes the mask
// tile flags (grid-stride over 1024 tiles of 64x64). One launch does all
// prep work -> 4 total dispatches in the graph.
// ---------------------------------------------------------------------------
__global__ __launch_bounds__(256) void prep_all(
    const float* __restrict__ s0, ushort_t* __restrict__ d0,
    const float* __restrict__ s1, ushort_t* __restrict__ d1,
    const float* __restrict__ s2, ushort_t* __restrict__ d2,
    const float* __restrict__ s3, ushort_t* __restrict__ d3,
    const float* __restrict__ s4, ushort_t* __restrict__ d4,
    const float* __restrict__ s5, ushort_t* __restrict__ d5,
    const float* __restrict__ s6, ushort_t* __restrict__ d6,
    const float* __restrict__ mask, int* __restrict__ flags, int nconv)
{
    const int z = blockIdx.z;
    const int t = threadIdx.x;

    if (z == nconv) {
        // ---- mask tile flags: wave-OR + LDS combine, 2 tiles per block ----
        __shared__ int sh[4];
        for (int tile = blockIdx.x; tile < 1024; tile += gridDim.x) {
            int qt = tile >> 5, kt = tile & 31;
            bool nz = false;
#pragma unroll
            for (int i = 0; i < 4; i++) {
                int idx = t + i * 256;           // 1024 float4: 64 rows x 16
                int row = idx >> 4, c4 = (idx & 15) * 4;
                float4 v = *(const float4*)(mask + (size_t)(qt * 64 + row) * SEQ
                                            + kt * 64 + c4);
                nz |= (v.x != 0.f) | (v.y != 0.f) | (v.z != 0.f) | (v.w != 0.f);
            }
            int wa = (int)(__any((int)nz) != 0);
            if ((t & 63) == 0) sh[t >> 6] = wa;
            __syncthreads();
            if (t == 0) flags[tile] = sh[0] | sh[1] | sh[2] | sh[3];
            __syncthreads();                     // protect sh reuse next tile
        }
        return;
    }

    const float* s = z == 0 ? s0 : z == 1 ? s1 : z == 2 ? s2 : z == 3 ? s3
                   : z == 4 ? s4 : z == 5 ? s5 : s6;
    ushort_t* d    = z == 0 ? d0 : z == 1 ? d1 : z == 2 ? d2 : z == 3 ? d3
                   : z == 4 ? d4 : z == 5 ? d5 : d6;
    const int n4 = (z < 4) ? 262144 : 1048576;
    int i = blockIdx.x * 256 + t;
    int stride = gridDim.x * 256;
    for (; i < n4; i += stride) {
        float4 v = ((const float4*)s)[i];
        uint2 pr;
        pr.x = cvtpk(v.x, v.y);
        pr.y = cvtpk(v.z, v.w);
        ((uint2*)d)[i] = pr;
    }
}

// ---------------------------------------------------------------------------
// GEMM staging, XOR-SWIZZLED LDS (r18-verified: conflicts 14.16M -> 0)
// ---------------------------------------------------------------------------
__device__ __forceinline__ void stageB_bf16(const ushort_t* __restrict__ B,
                                            int n0, int t, int w, int k0,
                                            ushort_t* sB)
{
#pragma unroll
    for (int r = 0; r < 2; r++) {
        int chunk = r * 256 + t;
        int row = chunk >> 3, cc = (chunk & 7) ^ (row & 7);
        gload16(B + (size_t)(n0 + row) * D_MODEL + k0 + cc * 8,
                &sB[(r * 256 + w * 64) * 8]);
    }
}

__device__ __forceinline__ void stageA_bf16(const ushort_t* __restrict__ A,
                                            int m0, int t, int w, int k0,
                                            ushort_t* sA)
{
#pragma unroll
    for (int r = 0; r < 4; r++) {
        int chunk = r * 256 + t;                   // 1024 chunks of 8 bf16
        int row = chunk >> 3, cc = (chunk & 7) ^ (row & 7);
        gload16(A + (size_t)(m0 + row) * D_MODEL + k0 + cc * 8,
                &sA[(r * 256 + w * 64) * 8]);
    }
}

__device__ __forceinline__ void stageA_f32(const float* __restrict__ A,
                                           int m0, int t, int k0,
                                           ushort_t* sA)
{
#pragma unroll
    for (int r = 0; r < 4; r++) {
        int chunk = r * 256 + t;
        int row = chunk >> 3, c = chunk & 7;
        const float* src = A + (size_t)(m0 + row) * D_MODEL + k0 + c * 8;
        float4 v0 = *(const float4*)src;
        float4 v1 = *(const float4*)(src + 4);
        u32x4 pw;
        pw[0] = cvtpk(v0.x, v0.y); pw[1] = cvtpk(v0.z, v0.w);
        pw[2] = cvtpk(v1.x, v1.y); pw[3] = cvtpk(v1.z, v1.w);
        int by = (row * 128 + c * 16) ^ ((row & 7) << 4);   // swizzled dest
        *(u32x4*)((char*)sA + by) = pw;
    }
}

// ---------------------------------------------------------------------------
// fused QKV projection (r20/21-verified): z=0 Aq->Qb (scaled), z=1 Ak->Kb,
// z=2 Av (or fp32 vx fallback) -> VT. 2-phase dbuf, swizzled LDS.
// ---------------------------------------------------------------------------
__global__ __launch_bounds__(256) void gemm_qkv(const ushort_t* __restrict__ Aq,
                                                const ushort_t* __restrict__ Ak,
                                                const ushort_t* __restrict__ Av,
                                                const float* __restrict__ vx,
                                                const ushort_t* __restrict__ Wq,
                                                const ushort_t* __restrict__ Wk,
                                                const ushort_t* __restrict__ Wv,
                                                ushort_t* __restrict__ Qo,
                                                ushort_t* __restrict__ Ko,
                                                ushort_t* __restrict__ VT)
{
    __shared__ ushort_t sA[2][128 * 64];
    __shared__ ushort_t sB[2][64 * 64];
    const int z = blockIdx.z;
    const ushort_t* Abf = z == 0 ? Aq : z == 1 ? Ak : Av;
    const ushort_t* W = z == 0 ? Wq : z == 1 ? Wk : Wv;
    const bool f32path = (z == 2) && (Av == nullptr);
    const int t = threadIdx.x, lane = t & 63, w = t >> 6;
    const int lr = lane & 15, lg = lane >> 4;
    const int wm = (w >> 1) * 64, wn = (w & 1) * 32;
    const int m0 = blockIdx.x * 128, n0 = blockIdx.y * 64;

    f32x4 acc[4][2];
    f32x4 zero = {0.f, 0.f, 0.f, 0.f};
#pragma unroll
    for (int i = 0; i < 4; i++)
#pragma unroll
        for (int j = 0; j < 2; j++) acc[i][j] = zero;

    stageB_bf16(W, n0, t, w, 0, &sB[0][0]);
    if (!f32path) stageA_bf16(Abf, m0, t, w, 0, &sA[0][0]);
    else          stageA_f32(vx, m0, t, 0, &sA[0][0]);
    __syncthreads();

    for (int it = 0; it < D_MODEL / 64; ++it) {
        const int cur = it & 1;
        const char* cA = (const char*)&sA[cur][0];
        const char* cB = (const char*)&sB[cur][0];
        const bool more = (it + 1 < D_MODEL / 64);

        us8 af[4][2], bfr[2][2];
#pragma unroll
        for (int i = 0; i < 4; i++)
#pragma unroll
            for (int ks = 0; ks < 2; ks++) {
                int row = wm + i * 16 + lr;
                af[i][ks] = *(const us8*)(cA + ((row * 128 + (ks * 32 + 8 * lg) * 2)
                                                ^ ((row & 7) << 4)));
            }
#pragma unroll
        for (int j = 0; j < 2; j++)
#pragma unroll
            for (int ks = 0; ks < 2; ks++) {
                int row = wn + j * 16 + lr;
                bfr[j][ks] = *(const us8*)(cB + ((row * 128 + (ks * 32 + 8 * lg) * 2)
                                                 ^ ((row & 7) << 4)));
            }

        if (more) {
            stageB_bf16(W, n0, t, w, (it + 1) * 64, &sB[cur ^ 1][0]);
            if (!f32path) stageA_bf16(Abf, m0, t, w, (it + 1) * 64, &sA[cur ^ 1][0]);
            else          stageA_f32(vx, m0, t, (it + 1) * 64, &sA[cur ^ 1][0]);
        }

#pragma unroll
        for (int i = 0; i < 4; i++)
#pragma unroll
            for (int j = 0; j < 2; j++)
#pragma unroll
                for (int ks = 0; ks < 2; ks++)
                    acc[i][j] = mfma16(af[i][ks], bfr[j][ks], acc[i][j]);

        __syncthreads();
    }

    if (z < 2) {
        ushort_t* C = z ? Ko : Qo;
        const float scale = z ? 1.0f : 0.125f * LOG2E;   // scores in log2 units
#pragma unroll
        for (int i = 0; i < 4; i++)
#pragma unroll
            for (int j = 0; j < 2; j++)
#pragma unroll
                for (int r = 0; r < 4; r++) {
                    int m = m0 + wm + i * 16 + 4 * lg + r;   // token (b*S+s)
                    int n = n0 + wn + j * 16 + lr;           // feature
                    int b = m >> 11, s = m & 2047;
                    int h = n >> 6, dh = n & 63;
                    C[(((size_t)(b * NH + h)) * SEQ + s) * DH + dh] = f2bf1(acc[i][j][r] * scale);
                }
    } else {
#pragma unroll
        for (int i = 0; i < 4; i++)
#pragma unroll
            for (int j = 0; j < 2; j++) {
                int m = m0 + wm + i * 16 + 4 * lg;           // s base; r adds 0..3
                int n = n0 + wn + j * 16 + lr;
                int b = m >> 11, s = m & 2047;
                int h = n >> 6, dh = n & 63;
                uint2 pr;
                pr.x = cvtpk(acc[i][j][0], acc[i][j][1]);
                pr.y = cvtpk(acc[i][j][2], acc[i][j][3]);
                *(uint2*)&VT[(((size_t)(b * NH + h)) * DH + dh) * SEQ + s] = pr;
            }
    }
}

// output projection: A bf16 [4096][1024] @ W0^T -> fp32 [4096][1024]
__global__ __launch_bounds__(256) void gemm_o(const ushort_t* __restrict__ A,
                                              const ushort_t* __restrict__ W,
                                              float* __restrict__ C)
{
    __shared__ ushort_t sA[2][128 * 64];
    __shared__ ushort_t sB[2][64 * 64];
    const int t = threadIdx.x, lane = t & 63, w = t >> 6;
    const int lr = lane & 15, lg = lane >> 4;
    const int wm = (w >> 1) * 64, wn = (w & 1) * 32;
    const int m0 = blockIdx.x * 128, n0 = blockIdx.y * 64;

    f32x4 acc[4][2];
    f32x4 zero = {0.f, 0.f, 0.f, 0.f};
#pragma unroll
    for (int i = 0; i < 4; i++)
#pragma unroll
        for (int j = 0; j < 2; j++) acc[i][j] = zero;

    stageA_bf16(A, m0, t, w, 0, &sA[0][0]);
    stageB_bf16(W, n0, t, w, 0, &sB[0][0]);
    __syncthreads();

    for (int it = 0; it < D_MODEL / 64; ++it) {
        const int cur = it & 1;
        const char* cA = (const char*)&sA[cur][0];
        const char* cB = (const char*)&sB[cur][0];

        us8 af[4][2], bfr[2][2];
#pragma unroll
        for (int i = 0; i < 4; i++)
#pragma unroll
            for (int ks = 0; ks < 2; ks++) {
                int row = wm + i * 16 + lr;
                af[i][ks] = *(const us8*)(cA + ((row * 128 + (ks * 32 + 8 * lg) * 2)
                                                ^ ((row & 7) << 4)));
            }
#pragma unroll
        for (int j = 0; j < 2; j++)
#pragma unroll
            for (int ks = 0; ks < 2; ks++) {
                int row = wn + j * 16 + lr;
                bfr[j][ks] = *(const us8*)(cB + ((row * 128 + (ks * 32 + 8 * lg) * 2)
                                                 ^ ((row & 7) << 4)));
            }

        if (it + 1 < D_MODEL / 64) {
            stageA_bf16(A, m0, t, w, (it + 1) * 64, &sA[cur ^ 1][0]);
            stageB_bf16(W, n0, t, w, (it + 1) * 64, &sB[cur ^ 1][0]);
        }

#pragma unroll
        for (int i = 0; i < 4; i++)
#pragma unroll
            for (int j = 0; j < 2; j++)
#pragma unroll
                for (int ks = 0; ks < 2; ks++)
                    acc[i][j] = mfma16(af[i][ks], bfr[j][ks], acc[i][j]);

        __syncthreads();
    }

#pragma unroll
    for (int i = 0; i < 4; i++)
#pragma unroll
        for (int j = 0; j < 2; j++)
#pragma unroll
            for (int r = 0; r < 4; r++) {
                int m = m0 + wm + i * 16 + 4 * lg + r;
                int n = n0 + wn + j * 16 + lr;
                C[(size_t)m * D_MODEL + n] = acc[i][j][r];
            }
}

// ---------------------------------------------------------------------------
// Flash attention (r15/r21 champion, single-pass): swapped-operand 32x32x16,
// KVBLK=64 dbuf, 32 KB LDS, launch_bounds(256,2), max-free softmax, permlane
// P-assembly, l on VALU, XCD swizzle, hoisted stage ptrs. r23 established
// this is a per-CU throughput floor (KV-split gave 0 at +8us cost).
// C/D layout (HW-verified): col=lane&31, row=(r&3)+8*(r>>2)+4*(lane>>5).
// ---------------------------------------------------------------------------
__global__ __launch_bounds__(256, 2) void attn_fwd(const ushort_t* __restrict__ Q,
                                                   const ushort_t* __restrict__ K,
                                                   const ushort_t* __restrict__ VT,
                                                   const float* __restrict__ mask,
                                                   const int* __restrict__ flags,
                                                   ushort_t* __restrict__ O)
{
    __shared__ ushort_t sK[2][64 * 64];     // 64 kv rows x 64 dh  (8 KB each)
    __shared__ ushort_t sVT[2][64 * 64];    // 64 dh rows x 64 kv

    const int t = threadIdx.x, lane = t & 63, w = t >> 6;
    const int l31 = lane & 31, lh = lane >> 5;
    const int id = blockIdx.x;
    const int bh = (id & 7) * 4 + ((id >> 3) >> 4);   // XCD-contiguous heads
    const int qt = (id >> 3) & 15;
    const int b = bh >> 4, h = bh & 15;
    const int q = qt * 128 + w * 32 + l31;   // lane's q row

    // mask-tile flags for this 128-row q block (2 flag rows ORed); bit = 64-col tile
    unsigned long long blt = __ballot(flags[(qt * 2 + lh) * 32 + l31] != 0);
    const unsigned int fl = (unsigned int)(blt | (blt >> 32));

    // Q fragments: B-operand rows = q, k(d)-slots 16*ks + 8*lh + e
    us8 qfr[4];
#pragma unroll
    for (int ks = 0; ks < 4; ks++)
        qfr[ks] = *(const us8*)(Q + ((size_t)bh * SEQ + q) * DH + ks * 16 + 8 * lh);

    f32x16 acc_o[2];
#pragma unroll
    for (int d = 0; d < 2; d++)
#pragma unroll
        for (int r = 0; r < 16; r++) acc_o[d][r] = 0.f;
    float acc_l = 0.f;

    const ushort_t* Kb = K + (size_t)bh * SEQ * DH;
    const ushort_t* Vb = VT + (size_t)bh * DH * SEQ;

    // hoisted per-thread staging source pointers (advance by const per tile)
    const ushort_t* kp[2];
    const ushort_t* vp[2];
#pragma unroll
    for (int r = 0; r < 2; r++) {
        int j = r * 256 + t;                 // 512 chunks of 16B per tensor
        int row = j >> 3, cc = (j & 7) ^ (row & 7);
        kp[r] = Kb + (size_t)row * DH + cc * 8;
        vp[r] = Vb + (size_t)row * SEQ + cc * 8;
    }

#define STAGE(kvt_, buf_)                                                     \
    {                                                                         \
        _Pragma("unroll")                                                     \
        for (int r = 0; r < 2; r++)                                           \
            gload16(kp[r] + (size_t)(kvt_) * (64 * DH),                       \
                    &sK[buf_][(r * 256 + w * 64) * 8]);                       \
        _Pragma("unroll")                                                     \
        for (int r = 0; r < 2; r++)                                           \
            gload16(vp[r] + (size_t)(kvt_) * 64,                              \
                    &sVT[buf_][(r * 256 + w * 64) * 8]);                      \
    }

    STAGE(0, 0);
    __syncthreads();

    for (int kvt = 0; kvt < SEQ / 64; ++kvt) {
        const int cur = kvt & 1;
        const char* cK = (const char*)sK[cur];
        const char* cV = (const char*)sVT[cur];

        // ---- S = K Q^T: sacc[kb][r] = S[kcol=kb*32+crow(r,lh)][q] ----
        f32x16 sacc[2];
#pragma unroll
        for (int kb = 0; kb < 2; kb++)
#pragma unroll
            for (int r = 0; r < 16; r++) sacc[kb][r] = 0.f;
        __builtin_amdgcn_s_setprio(1);
#pragma unroll
        for (int ks = 0; ks < 4; ks++)
#pragma unroll
            for (int kb = 0; kb < 2; kb++) {
                int row = kb * 32 + l31;
                int by = (row * 128 + (ks * 16 + 8 * lh) * 2) ^ ((row & 7) << 4);
                us8 kf = *(const us8*)(cK + by);
                sacc[kb] = mfma32(kf, qfr[ks], sacc[kb]);
            }
        __builtin_amdgcn_s_setprio(0);

        // ---- V-frag reads (last ds_reads of this tile) ----
        us8 vf[4][2];
#pragma unroll
        for (int ks = 0; ks < 4; ks++)
#pragma unroll
            for (int dblk = 0; dblk < 2; dblk++) {
                int row = dblk * 32 + l31;
                int by = (row * 128 + (ks * 16 + 8 * lh) * 2) ^ ((row & 7) << 4);
                vf[ks][dblk] = *(const us8*)(cV + by);
            }

        // ---- stage next tile; loads hide under softmax + PV ----
        if (kvt + 1 < SEQ / 64) STAGE(kvt + 1, cur ^ 1);

        // ---- additive mask (log2; skipped when 64-col tile all-zero) ----
        if ((fl >> kvt) & 1u) {
#pragma unroll
            for (int kb = 0; kb < 2; kb++)
#pragma unroll
                for (int r = 0; r < 16; r++) {
                    int kcol = kb * 32 + (r & 3) + 8 * (r >> 2) + 4 * lh;
                    sacc[kb][r] += mask[(size_t)q * SEQ + kvt * 64 + kcol] * LOG2E;
                }
        }

        // ---- P = exp2(S) in place (max-free); l partial sum ----
        float rs = 0.f;
#pragma unroll
        for (int kb = 0; kb < 2; kb++)
#pragma unroll
            for (int r = 0; r < 16; r++) {
                float p = exp2_fast(sacc[kb][r]);
                sacc[kb][r] = p;
                rs += p;
            }
        rs += __shfl_xor(rs, 32);
        acc_l += rs;

        // ---- PV: P B-frags via cvt_pk + permlane32_swap (verified r12) ----
        __builtin_amdgcn_s_setprio(1);
#pragma unroll
        for (int ks = 0; ks < 4; ks++) {
            const int kb = ks >> 1, u = ks & 1;
            unsigned int W0 = cvtpk(sacc[kb][8 * u + 0], sacc[kb][8 * u + 1]);
            unsigned int W1 = cvtpk(sacc[kb][8 * u + 2], sacc[kb][8 * u + 3]);
            unsigned int W2 = cvtpk(sacc[kb][8 * u + 4], sacc[kb][8 * u + 5]);
            unsigned int W3 = cvtpk(sacc[kb][8 * u + 6], sacc[kb][8 * u + 7]);
            asm("v_permlane32_swap_b32 %0, %1" : "+v"(W0), "+v"(W2));
            asm("v_permlane32_swap_b32 %0, %1" : "+v"(W1), "+v"(W3));
            u32x4 pw;
            pw[0] = W0; pw[1] = W1; pw[2] = W2; pw[3] = W3;
            us8 pf = __builtin_bit_cast(us8, pw);
#pragma unroll
            for (int dblk = 0; dblk < 2; dblk++)
                acc_o[dblk] = mfma32(vf[ks][dblk], pf, acc_o[dblk]);
        }
        __builtin_amdgcn_s_setprio(0);

        __syncthreads();   // drains stage(kvt+1); protects buf reuse
    }

    // ---- normalize + write [B*S][D] bf16 (d = dblk*32 + 8g + 4lh + 0..3) ----
    float inv = 1.f / acc_l;
    ushort_t* Orow = O + ((size_t)(b * SEQ) + q) * D_MODEL + h * DH;
#pragma unroll
    for (int dblk = 0; dblk < 2; dblk++)
#pragma unroll
        for (int g = 0; g < 4; g++) {
            unsigned int lo = cvtpk(acc_o[dblk][4 * g + 0] * inv,
                                    acc_o[dblk][4 * g + 1] * inv);
            unsigned int hi = cvtpk(acc_o[dblk][4 * g + 2] * inv,
                                    acc_o[dblk][4 * g + 3] * inv);
            uint2 pr; pr.x = lo; pr.y = hi;
            *(uint2*)(Orow + dblk * 32 + 8 * g + 4 * lh) = pr;
        }
#undef STAGE
}

// ---------------------------------------------------------------------------
extern "C" void kernel_launch(void* const* d_in, const int* in_sizes, int n_in,
                              void* d_out, int out_size, void* d_ws, size_t ws_size,
                              hipStream_t stream)
{
    const float* qx   = (const float*)d_in[0];
    const float* kx   = (const float*)d_in[1];
    const float* vx   = (const float*)d_in[2];
    const float* mask = (const float*)d_in[3];
    const float* wq   = (const float*)d_in[4];
    const float* wk   = (const float*)d_in[5];
    const float* wv   = (const float*)d_in[6];
    const float* w0   = (const float*)d_in[7];
    float* out = (float*)d_out;

    char* ws = (char*)d_ws;
    const size_t MB = 1024 * 1024;
    ushort_t* Aq = (ushort_t*)(ws);                 // qx bf16, 8 MB
    ushort_t* Ak = (ushort_t*)(ws + 8 * MB);        // kx bf16, 8 MB; dead after
    ushort_t* AO = (ushort_t*)(ws + 8 * MB);        //   gemm_qkv -> AO reuses it
    ushort_t* Wq = (ushort_t*)(ws + 16 * MB);       // 2 MB each
    ushort_t* Wk = (ushort_t*)(ws + 18 * MB);
    ushort_t* Wv = (ushort_t*)(ws + 20 * MB);
    ushort_t* W0 = (ushort_t*)(ws + 22 * MB);
    ushort_t* VT = (ushort_t*)(ws + 24 * MB);       // [B,H,Dh,S] bf16, 8 MB

    // ws probe (r21-proven >=41 MB available on this harness): Av enables the
    // all-bf16 gemm_qkv; fallback = r20 configuration (z=2 fp32 in-kernel).
    const bool bigws = (ws_size >= 41 * MB);
    ushort_t* Av = bigws ? (ushort_t*)(ws + 32 * MB) : nullptr;   // 8 MB
    int* flags   = (int*)(ws + (bigws ? 40 * MB : 32 * MB));      // 4 KB

    // Q and K (bf16, [B,H,S,Dh]) live in d_out until attn consumes them
    ushort_t* Qb = (ushort_t*)d_out;
    ushort_t* Kb = (ushort_t*)d_out + 4 * MB;       // +8 MB bytes

    // ALL prep in one launch: conversions (z < nconv) + mask flags (z == nconv)
    const int nconv = bigws ? 7 : 6;
    prep_all<<<dim3(512, 1, nconv + 1), 256, 0, stream>>>(
        wq, Wq, wk, Wk, wv, Wv, w0, W0,
        qx, Aq, kx, Ak, vx, bigws ? Av : Aq,
        mask, flags, nconv);

    // fused QKV projections: all-bf16 when bigws, else z=2 fp32 in-kernel
    gemm_qkv<<<dim3(32, 16, 3), 256, 0, stream>>>(Aq, Ak, Av, vx,
                                                  Wq, Wk, Wv, Qb, Kb, VT);

    attn_fwd<<<512, 256, 0, stream>>>(Qb, Kb, VT, mask, flags, AO);

    gemm_o<<<dim3(32, 16), 256, 0, stream>>>(AO, W0, out);
}